// Round 3
// baseline (18923.531 us; speedup 1.0000x reference)
//
#include <hip/hip_runtime.h>

// AdderNet-EDSR on MI355X. Pure VALU-fp32 workload (L1-dist has no matmul form).
// v3: conflict-free LDS (row stride 80 == 16 mod 32 -> exact 2-way = free),
// 192-thr blocks (3 waves x one 4x16 subtile, 4 oc) -> mid grid 768 = exactly
// 3 blocks/CU, T14 async staging (global->reg issued before compute, ds_write
// after barrier), shift-only staging addressing, fully-unrolled inner loop
// (all DS reads base+imm, weights via wave-uniform ds_read_b128 broadcast).

enum { M_PLAIN = 0, M_RELU = 1, M_RES = 2, M_ADD = 3, M_PS = 4, M_HEAD = 5 };

__device__ __forceinline__ float mean_of(int c) {
    return c == 0 ? 0.4488f : (c == 1 ? 0.4371f : 0.404f);
}

// ---- weight transpose: w[oc][ic][k] -> wt[(ic*9+k)*COUT + oc], per layer ----
template <int CIN, int COUT>
__global__ __launch_bounds__(256) void wtr_kernel(const float* __restrict__ w,
                                                  float* __restrict__ wt) {
    const int L = CIN * COUT * 9;
    const int id = blockIdx.x * 256 + threadIdx.x;
    const float* src = w + blockIdx.y * L;
    float* dst = wt + blockIdx.y * L;
    if (id < L) {
        const int oc = id / (CIN * 9);
        const int r  = id % (CIN * 9);
        dst[r * COUT + oc] = src[id];
    }
}

// ---- adder layer ----
// block = 192 thr = 3 waves. Tile: 4 rows x 48 cols x 4 oc. Wave wv covers cols
// wv*16..wv*16+15 (lane&15) x rows (lane>>4). grid = (12 row-bands, COUT/4, 4 batch).
template <int CIN, int COUT, int MODE>
__global__ __launch_bounds__(192) void adder_kernel(const float* __restrict__ in,
                                                    const float* __restrict__ wt,
                                                    const float* __restrict__ res,
                                                    float* __restrict__ out) {
    constexpr int ICC = (CIN < 16) ? CIN : 16;
    constexpr int NCH = CIN / ICC;
    constexpr int RIT = ICC * 2;   // staging row-iterations (3 rows each)
    constexpr int NW4 = ICC * 9;   // weight float4s per chunk

    __shared__ __align__(16) float s_in[ICC][6][80];  // rows y0-1..y0+4, cols -1..48 (+pad)
    __shared__ __align__(16) float s_w[ICC][9][4];    // [ic][k][oc-in-block]

    const int tid  = threadIdx.x;
    const int wv   = tid >> 6;
    const int lane = tid & 63;
    const int ly = lane >> 4;
    const int lx = (lane & 15) + wv * 16;  // 0..47

    const int y0  = blockIdx.x * 4;
    const int ocb = blockIdx.y;
    const int b   = blockIdx.z;
    const int y = y0 + ly, x = lx;
    const int oc0 = ocb * 4;

    // ---- res prefetch (overlaps everything) ----
    const int obase = ((b * COUT + oc0) * 48 + y) * 48 + x;
    float rsv[4] = {0.f, 0.f, 0.f, 0.f};
    if (MODE == M_RES || MODE == M_ADD) {
#pragma unroll
        for (int o = 0; o < 4; ++o) rsv[o] = res[obase + o * 2304];
    }

    // ---- staging lane geometry (shift/and only) ----
    const int scc   = tid & 63;   // staging col 0..63 (valid < 50)
    const int srow0 = tid >> 6;   // 0..2 (3 rows per iteration)
    const int gx    = scc - 1;
    const bool colok = (scc >= 1) && (scc <= 48);
    const int gyA = y0 + srow0 - 1, gyB = gyA + 3;
    const bool vA = colok && ((unsigned)gyA < 48u);
    const bool vB = colok && ((unsigned)gyB < 48u);
    const int offA = gyA * 48 + gx, offB = offA + 144;

    const int wic = tid / 9, wkk = tid - wic * 9;  // weight f4 decomposition

    float vin[RIT];
    float4 vw = {0.f, 0.f, 0.f, 0.f};

    auto stage_load = [&](int ch) {
        const float* base = in + (size_t)(b * CIN + ch * ICC) * 2304;
#pragma unroll
        for (int k = 0; k < RIT; ++k) {
            const bool odd = k & 1;
            float v = 0.f;
            if (odd ? vB : vA) {
                v = base[(k >> 1) * 2304 + (odd ? offB : offA)];
                if (MODE == M_HEAD) v -= mean_of(k >> 1);
            }
            vin[k] = v;
        }
        if (tid < NW4)
            vw = *(const float4*)&wt[((size_t)(ch * ICC + wic) * 9 + wkk) * COUT + oc0];
    };
    auto stage_write = [&]() {
#pragma unroll
        for (int k = 0; k < RIT; ++k)
            if (scc < 50) s_in[k >> 1][srow0 + 3 * (k & 1)][scc] = vin[k];
        if (tid < NW4) *(float4*)&s_w[wic][wkk][0] = vw;
    };

    float acc0 = 0.f, acc1 = 0.f, acc2 = 0.f, acc3 = 0.f;

    stage_load(0);
    stage_write();
    __syncthreads();

    for (int ch = 0; ch < NCH; ++ch) {
        if (ch + 1 < NCH) stage_load(ch + 1);  // issue global loads early (T14)

#pragma unroll
        for (int ic = 0; ic < ICC; ++ic) {
            float f[3][3];
#pragma unroll
            for (int dy = 0; dy < 3; ++dy)
#pragma unroll
                for (int dx = 0; dx < 3; ++dx) f[dy][dx] = s_in[ic][ly + dy][lx + dx];
#pragma unroll
            for (int kk = 0; kk < 9; ++kk) {
                const float4 w4 = *(const float4*)&s_w[ic][kk][0];  // uniform -> broadcast
                const float fv = f[kk / 3][kk % 3];
                acc0 -= fabsf(fv - w4.x);
                acc1 -= fabsf(fv - w4.y);
                acc2 -= fabsf(fv - w4.z);
                acc3 -= fabsf(fv - w4.w);
            }
        }
        __syncthreads();
        if (ch + 1 < NCH) {
            stage_write();
            __syncthreads();
        }
    }

    // ---- epilogue ----
    const float accs[4] = {acc0, acc1, acc2, acc3};
#pragma unroll
    for (int o = 0; o < 4; ++o) {
        float v = accs[o];
        if (MODE == M_RELU) v = fmaxf(v, 0.f);
        if (MODE == M_RES) v = rsv[o] + 0.1f * v;
        if (MODE == M_ADD) v = rsv[o] + v;
        if (MODE == M_PS) {
            // pixel-shuffle r=2: oc = ocb*4+o -> plane ocb, dy=o>>1, dx=o&1
            const int idx = ((b * 64 + ocb) * 96 + 2 * y + (o >> 1)) * 96 + 2 * x + (o & 1);
            out[idx] = v;
        } else {
            out[obase + o * 2304] = v;
        }
    }
}

// ---- tail: real conv 64->3 over ps[4][64][96][96], + bias + mean ----
__global__ __launch_bounds__(256) void tail_kernel(const float* __restrict__ ps,
                                                   const float* __restrict__ tw,
                                                   const float* __restrict__ tb,
                                                   float* __restrict__ out) {
    __shared__ float s_w[1728];  // [ic*9+k][oc]
    const int tid = threadIdx.x;
    for (int i = tid; i < 1728; i += 256) {
        const int oc = i / 576, rem = i % 576;
        s_w[rem * 3 + oc] = tw[i];
    }
    __syncthreads();

    const int gid = blockIdx.x * 256 + tid;  // 36864 px
    const int b = gid / 9216;
    const int p = gid % 9216;
    const int Y = p / 96, X = p % 96;

    float a0 = tb[0], a1 = tb[1], a2 = tb[2];
    for (int ic = 0; ic < 64; ++ic) {
        const float* base = ps + (b * 64 + ic) * 9216;
#pragma unroll
        for (int kk = 0; kk < 9; ++kk) {
            const int yy = Y + kk / 3 - 1, xx = X + kk % 3 - 1;
            float fv = 0.f;
            if ((unsigned)yy < 96u && (unsigned)xx < 96u) fv = base[yy * 96 + xx];
            const float* wr = &s_w[(ic * 9 + kk) * 3];
            a0 += fv * wr[0];
            a1 += fv * wr[1];
            a2 += fv * wr[2];
        }
    }
    out[((b * 3 + 0) * 96 + Y) * 96 + X] = a0 + mean_of(0);
    out[((b * 3 + 1) * 96 + Y) * 96 + X] = a1 + mean_of(1);
    out[((b * 3 + 2) * 96 + Y) * 96 + X] = a2 + mean_of(2);
}

extern "C" void kernel_launch(void* const* d_in, const int* in_sizes, int n_in,
                              void* d_out, int out_size, void* d_ws, size_t ws_size,
                              hipStream_t stream) {
    const float* x      = (const float*)d_in[0];
    const float* head_w = (const float*)d_in[1];
    const float* rb_w1  = (const float*)d_in[2];
    const float* rb_w2  = (const float*)d_in[3];
    const float* body_w = (const float*)d_in[4];
    const float* up_w   = (const float*)d_in[5];
    const float* tail_w = (const float*)d_in[6];
    const float* tail_b = (const float*)d_in[7];
    float* out = (float*)d_out;

    // ws layout (floats). S = one activation plane (4*64*48*48 = 589824).
    // ps (4S) aliases s0..s3, all dead by the time `up` runs.
    constexpr int S = 589824;
    float* ws = (float*)d_ws;
    float* s0 = ws;          // h
    float* s1 = ws + 1 * S;  // b-chain
    float* s2 = ws + 2 * S;  // b-chain
    float* s3 = ws + 3 * S;  // r
    float* s4 = ws + 4 * S;  // body output (up input)
    float* ps = ws;          // spans s0..s3
    float* wtH = ws + 5 * S;       // 1728
    float* wt1 = wtH + 1728;       // 8 x 36864
    float* wt2 = wt1 + 8 * 36864;  // 8 x 36864
    float* wtB = wt2 + 8 * 36864;  // 36864
    float* wtU = wtB + 36864;      // 147456

    wtr_kernel<3, 64><<<dim3(7, 1), 256, 0, stream>>>(head_w, wtH);
    wtr_kernel<64, 64><<<dim3(144, 8), 256, 0, stream>>>(rb_w1, wt1);
    wtr_kernel<64, 64><<<dim3(144, 8), 256, 0, stream>>>(rb_w2, wt2);
    wtr_kernel<64, 64><<<dim3(144, 1), 256, 0, stream>>>(body_w, wtB);
    wtr_kernel<64, 256><<<dim3(576, 1), 256, 0, stream>>>(up_w, wtU);

    const dim3 blk(192);
    const dim3 gmid(12, 16, 4);  // 768 blocks = exactly 3/CU

    adder_kernel<3, 64, M_HEAD><<<gmid, blk, 0, stream>>>(x, wtH, nullptr, s0);

    const float* cur = s0;
    float* bufs[2] = {s1, s2};
    for (int k = 0; k < 8; ++k) {
        adder_kernel<64, 64, M_RELU><<<gmid, blk, 0, stream>>>(cur, wt1 + k * 36864,
                                                               nullptr, s3);
        adder_kernel<64, 64, M_RES><<<gmid, blk, 0, stream>>>(s3, wt2 + k * 36864, cur,
                                                              bufs[k & 1]);
        cur = bufs[k & 1];
    }
    adder_kernel<64, 64, M_ADD><<<gmid, blk, 0, stream>>>(cur, wtB, s0, s4);
    adder_kernel<64, 256, M_PS><<<dim3(12, 64, 4), blk, 0, stream>>>(s4, wtU, nullptr, ps);
    tail_kernel<<<dim3(144), dim3(256), 0, stream>>>(ps, tail_w, tail_b, out);
}

// Round 5
// 920.854 us; speedup vs baseline: 20.5500x; 20.5500x over previous
//
#include <hip/hip_runtime.h>

// AdderNet-EDSR on MI355X. L1-dist has no matmul form -> VALU-bound.
// v4b: v2's simple staging (low VGPR), v3's geometry (192thr/3-wave blocks,
// 4x48 tile, 768 blocks = exactly 3/CU, LDS stride 80 == 16 mod 32 -> exact
// 2-way bank access = free), f16-packed inner loop: 2 ics per u32, per 2
// pairs = v_pk_add_f16 + v_and_b32 (packed abs) + v_dot2_f32_f16(|d|,(-1,-1))
// accumulating in f32 -> 1.5 inst/pair vs 2 for scalar f32, half LDS traffic.
// (v4 compile fix: cvt_pkrtz returns __fp16 ext-vector, not _Float16.)

enum { M_PLAIN = 0, M_RELU = 1, M_RES = 2, M_ADD = 3, M_PS = 4, M_HEAD = 5 };

typedef __fp16 h2 __attribute__((ext_vector_type(2)));

__device__ __forceinline__ float mean_of(int c) {
    return c == 0 ? 0.4488f : (c == 1 ? 0.4371f : 0.404f);
}

// ---- weight transform: w[oc][ic][k] (f32) -> wt[(icp*9+kk)*COUT + oc] (u32 =
// packed f16 pair over ic = 2*icp, 2*icp+1; odd tail padded with 0). ----
template <int CIN, int COUT>
__global__ __launch_bounds__(256) void wtr2_kernel(const float* __restrict__ w,
                                                   unsigned* __restrict__ wt) {
    constexpr int ICP = (CIN + 1) / 2;
    const int L = ICP * 9 * COUT;
    const int id = blockIdx.x * 256 + threadIdx.x;
    if (id >= L) return;
    const float* src = w + (size_t)blockIdx.y * COUT * CIN * 9;
    unsigned* dst = wt + (size_t)blockIdx.y * L;
    const int oc = id % COUT;
    const int t = id / COUT;
    const int kk = t % 9, icp = t / 9;
    const int ic0 = icp * 2;
    const float a = src[(oc * CIN + ic0) * 9 + kk];
    const float b = (ic0 + 1 < CIN) ? src[(oc * CIN + ic0 + 1) * 9 + kk] : 0.f;
    h2 p = __builtin_amdgcn_cvt_pkrtz(a, b);
    dst[id] = __builtin_bit_cast(unsigned, p);
}

// ---- adder layer ----
// block = 192 thr = 3 waves; tile 4 rows x 48 cols x 4 oc; wave wv covers cols
// wv*16..wv*16+15, rows lane>>4. grid = (12 row-bands, COUT/4, batch 4).
template <int CIN, int COUT, int MODE>
__global__ __launch_bounds__(192) void adder_kernel(const float* __restrict__ in,
                                                    const unsigned* __restrict__ wt,
                                                    const float* __restrict__ res,
                                                    float* __restrict__ out) {
    constexpr int ICPC = (CIN >= 64) ? 8 : 2;     // ic-pairs per chunk
    constexpr int NCH = ((CIN + 1) / 2) / ICPC;   // 4 for CIN=64, 1 for CIN=3
    __shared__ unsigned s_in[ICPC][6][80];        // stride 80: 2-way banks = free
    __shared__ __align__(16) unsigned s_w[ICPC][9][4];

    const int tid = threadIdx.x;
    const int wv = tid >> 6;
    const int lane = tid & 63;
    const int ly = lane >> 4;
    const int lx = (lane & 15) + wv * 16;  // 0..47

    const int y0 = blockIdx.x * 4;
    const int ocb = blockIdx.y;
    const int b = blockIdx.z;
    const int y = y0 + ly, x = lx;
    const int oc0 = ocb * 4;

    const int obase = ((b * COUT + oc0) * 48 + y) * 48 + x;
    float rsv[4] = {0.f, 0.f, 0.f, 0.f};
    if (MODE == M_RES || MODE == M_ADD) {
#pragma unroll
        for (int o = 0; o < 4; ++o) rsv[o] = res[obase + o * 2304];
    }

    float acc0 = 0.f, acc1 = 0.f, acc2 = 0.f, acc3 = 0.f;
    const unsigned AM = 0x7fff7fffu;      // packed f16 abs mask
    const unsigned MONES = 0xbc00bc00u;   // h2{-1,-1}

    for (int ch = 0; ch < NCH; ++ch) {
        // ---- stage input (f32 -> packed f16 pair over 2 ics) ----
        const float* base = in + (size_t)(b * CIN + ch * ICPC * 2) * 2304;
        for (int i = tid; i < ICPC * 300; i += 192) {
            const int icp = i / 300, r = i % 300, rr = r / 50, cc = r % 50;
            const int gy = y0 + rr - 1, gx = cc - 1;
            float va = 0.f, vb = 0.f;
            if ((unsigned)gy < 48u && (unsigned)gx < 48u) {
                const float* p = base + icp * 2 * 2304 + gy * 48 + gx;
                va = p[0];
                if (!(CIN == 3 && icp == 1)) vb = p[2304];
                if (MODE == M_HEAD) {
                    va -= mean_of(2 * icp);
                    if (!(CIN == 3 && icp == 1)) vb -= mean_of(2 * icp + 1);
                }
            }
            h2 pk = __builtin_amdgcn_cvt_pkrtz(va, vb);
            s_in[icp][rr][cc] = __builtin_bit_cast(unsigned, pk);
        }
        // ---- stage weights ----
        for (int i = tid; i < ICPC * 36; i += 192) {
            const int icp = i / 36, r = i % 36, kk = r >> 2, j = r & 3;
            s_w[icp][kk][j] = wt[((size_t)(ch * ICPC + icp) * 9 + kk) * COUT + oc0 + j];
        }
        __syncthreads();

#pragma unroll
        for (int icp = 0; icp < ICPC; ++icp) {
            unsigned f[3][3];
#pragma unroll
            for (int dy = 0; dy < 3; ++dy)
#pragma unroll
                for (int dx = 0; dx < 3; ++dx) f[dy][dx] = s_in[icp][ly + dy][lx + dx];
#pragma unroll
            for (int kk = 0; kk < 9; ++kk) {
                const uint4 w4 = *(const uint4*)&s_w[icp][kk][0];  // wave-uniform
                const h2 fv = __builtin_bit_cast(h2, f[kk / 3][kk % 3]);
                {
                    h2 d = fv - __builtin_bit_cast(h2, w4.x);
                    unsigned u = __builtin_bit_cast(unsigned, d) & AM;
                    asm("v_dot2_f32_f16 %0, %1, %2, %0" : "+v"(acc0) : "v"(u), "v"(MONES));
                }
                {
                    h2 d = fv - __builtin_bit_cast(h2, w4.y);
                    unsigned u = __builtin_bit_cast(unsigned, d) & AM;
                    asm("v_dot2_f32_f16 %0, %1, %2, %0" : "+v"(acc1) : "v"(u), "v"(MONES));
                }
                {
                    h2 d = fv - __builtin_bit_cast(h2, w4.z);
                    unsigned u = __builtin_bit_cast(unsigned, d) & AM;
                    asm("v_dot2_f32_f16 %0, %1, %2, %0" : "+v"(acc2) : "v"(u), "v"(MONES));
                }
                {
                    h2 d = fv - __builtin_bit_cast(h2, w4.w);
                    unsigned u = __builtin_bit_cast(unsigned, d) & AM;
                    asm("v_dot2_f32_f16 %0, %1, %2, %0" : "+v"(acc3) : "v"(u), "v"(MONES));
                }
            }
        }
        if (ch + 1 < NCH) __syncthreads();
    }

    // ---- epilogue ----
    const float accs[4] = {acc0, acc1, acc2, acc3};
#pragma unroll
    for (int o = 0; o < 4; ++o) {
        float v = accs[o];
        if (MODE == M_RELU) v = fmaxf(v, 0.f);
        if (MODE == M_RES) v = rsv[o] + 0.1f * v;
        if (MODE == M_ADD) v = rsv[o] + v;
        if (MODE == M_PS) {
            const int idx =
                ((b * 64 + ocb) * 96 + 2 * y + (o >> 1)) * 96 + 2 * x + (o & 1);
            out[idx] = v;
        } else {
            out[obase + o * 2304] = v;
        }
    }
}

// ---- tail: real conv 64->3 over ps[4][64][96][96] (f32), + bias + mean ----
__global__ __launch_bounds__(256) void tail_kernel(const float* __restrict__ ps,
                                                   const float* __restrict__ tw,
                                                   const float* __restrict__ tb,
                                                   float* __restrict__ out) {
    __shared__ float s_w[1728];  // [ic*9+k][oc]
    const int tid = threadIdx.x;
    for (int i = tid; i < 1728; i += 256) {
        const int oc = i / 576, rem = i % 576;
        s_w[rem * 3 + oc] = tw[i];
    }
    __syncthreads();

    const int gid = blockIdx.x * 256 + tid;  // 36864 px
    const int b = gid / 9216;
    const int p = gid % 9216;
    const int Y = p / 96, X = p % 96;

    float a0 = tb[0], a1 = tb[1], a2 = tb[2];
    for (int ic = 0; ic < 64; ++ic) {
        const float* base = ps + (b * 64 + ic) * 9216;
#pragma unroll
        for (int kk = 0; kk < 9; ++kk) {
            const int yy = Y + kk / 3 - 1, xx = X + kk % 3 - 1;
            float fv = 0.f;
            if ((unsigned)yy < 96u && (unsigned)xx < 96u) fv = base[yy * 96 + xx];
            const float* wr = &s_w[(ic * 9 + kk) * 3];
            a0 += fv * wr[0];
            a1 += fv * wr[1];
            a2 += fv * wr[2];
        }
    }
    out[((b * 3 + 0) * 96 + Y) * 96 + X] = a0 + mean_of(0);
    out[((b * 3 + 1) * 96 + Y) * 96 + X] = a1 + mean_of(1);
    out[((b * 3 + 2) * 96 + Y) * 96 + X] = a2 + mean_of(2);
}

extern "C" void kernel_launch(void* const* d_in, const int* in_sizes, int n_in,
                              void* d_out, int out_size, void* d_ws, size_t ws_size,
                              hipStream_t stream) {
    const float* x      = (const float*)d_in[0];
    const float* head_w = (const float*)d_in[1];
    const float* rb_w1  = (const float*)d_in[2];
    const float* rb_w2  = (const float*)d_in[3];
    const float* body_w = (const float*)d_in[4];
    const float* up_w   = (const float*)d_in[5];
    const float* tail_w = (const float*)d_in[6];
    const float* tail_b = (const float*)d_in[7];
    float* out = (float*)d_out;

    // ws: 5 f32 activation planes (S each), then packed-f16 weight area (u32).
    constexpr int S = 589824;
    float* ws = (float*)d_ws;
    float* s0 = ws;          // h
    float* s1 = ws + 1 * S;  // b-chain
    float* s2 = ws + 2 * S;  // b-chain
    float* s3 = ws + 3 * S;  // r
    float* s4 = ws + 4 * S;  // body output (up input)
    float* ps = ws;          // 4S, aliases s0..s3 (all dead when up runs)
    unsigned* wtH = (unsigned*)(ws + 5 * S);  // 2*9*64   = 1152
    unsigned* wt1 = wtH + 1152;               // 8 layers x 32*9*64 = 18432
    unsigned* wt2 = wt1 + 8 * 18432;
    unsigned* wtB = wt2 + 8 * 18432;          // 18432
    unsigned* wtU = wtB + 18432;              // 32*9*256 = 73728

    wtr2_kernel<3, 64><<<dim3(5, 1), 256, 0, stream>>>(head_w, wtH);
    wtr2_kernel<64, 64><<<dim3(72, 8), 256, 0, stream>>>(rb_w1, wt1);
    wtr2_kernel<64, 64><<<dim3(72, 8), 256, 0, stream>>>(rb_w2, wt2);
    wtr2_kernel<64, 64><<<dim3(72, 1), 256, 0, stream>>>(body_w, wtB);
    wtr2_kernel<64, 256><<<dim3(288, 1), 256, 0, stream>>>(up_w, wtU);

    const dim3 blk(192);
    const dim3 gmid(12, 16, 4);  // 768 blocks = exactly 3/CU

    adder_kernel<3, 64, M_HEAD><<<gmid, blk, 0, stream>>>(x, wtH, nullptr, s0);

    const float* cur = s0;
    float* bufs[2] = {s1, s2};
    for (int k = 0; k < 8; ++k) {
        adder_kernel<64, 64, M_RELU><<<gmid, blk, 0, stream>>>(cur, wt1 + k * 18432,
                                                               nullptr, s3);
        adder_kernel<64, 64, M_RES><<<gmid, blk, 0, stream>>>(s3, wt2 + k * 18432, cur,
                                                              bufs[k & 1]);
        cur = bufs[k & 1];
    }
    adder_kernel<64, 64, M_ADD><<<gmid, blk, 0, stream>>>(cur, wtB, s0, s4);
    adder_kernel<64, 256, M_PS><<<dim3(12, 64, 4), blk, 0, stream>>>(s4, wtU, nullptr, ps);
    tail_kernel<<<dim3(144), dim3(256), 0, stream>>>(ps, tail_w, tail_b, out);
}

// Round 6
// 823.040 us; speedup vs baseline: 22.9922x; 1.1188x over previous
//
#include <hip/hip_runtime.h>

// AdderNet-EDSR on MI355X. L1-dist has no matmul form -> VALU/LDS-bound.
// v6: LDS-pipe diet. (1) weights read via uniform s_load (off the LDS pipe,
// was 9 ds_read_b128/icp), (2) activations persistently packed f16x2 with a
// zero halo ([icp][50][64] u32 planes) so staging is a divmod-free coalesced
// u32 copy and the 16x per-layer f32->f16 reconversion disappears, (3) fdot2
// builtin (1.5 inst/pair, f32 accum), (4) tail split over 4 ic-quarters with
// f32 atomicAdd for 4x the waves.

enum { M_PLAIN = 0, M_RELU = 1, M_RES = 2, M_ADD = 3, M_PS = 4, M_HEAD = 5 };

typedef __fp16 h2 __attribute__((ext_vector_type(2)));

__device__ __forceinline__ float mean_of(int c) {
    return c == 0 ? 0.4488f : (c == 1 ? 0.4371f : 0.404f);
}

__device__ __forceinline__ float fdot2_acc(unsigned u, float acc) {
    const h2 mh = {(__fp16)-1.0f, (__fp16)-1.0f};
#if __has_builtin(__builtin_amdgcn_fdot2)
    return __builtin_amdgcn_fdot2(__builtin_bit_cast(h2, u), mh, acc, false);
#else
    const unsigned MONES = 0xbc00bc00u;
    asm("v_dot2_f32_f16 %0, %1, %2, %0" : "+v"(acc) : "v"(u), "v"(MONES));
    return acc;
#endif
}

// ---- zero helper (grid-stride uint4) ----
__global__ __launch_bounds__(256) void zero_kernel(uint4* __restrict__ p, int n4) {
    const uint4 z = {0u, 0u, 0u, 0u};
    for (int i = blockIdx.x * 256 + threadIdx.x; i < n4; i += gridDim.x * 256)
        p[i] = z;
}

// ---- pack x - mean into px[b][icp=2][50][64] (halo included = 0) ----
__global__ __launch_bounds__(256) void packx_kernel(const float* __restrict__ x,
                                                    unsigned* __restrict__ px) {
    const int id = blockIdx.x * 256 + threadIdx.x;  // 4*2*3200 = 25600
    if (id >= 25600) return;
    const int b = id / 6400, r = id % 6400;
    const int icp = r / 3200, r2 = r % 3200;
    const int yy = r2 / 64, xx = r2 % 64;
    const int y = yy - 1, gx = xx - 1;
    float va = 0.f, vb = 0.f;
    if ((unsigned)y < 48u && (unsigned)gx < 48u) {
        va = x[((b * 3 + 2 * icp) * 48 + y) * 48 + gx] - mean_of(2 * icp);
        if (icp == 0) vb = x[((b * 3 + 1) * 48 + y) * 48 + gx] - mean_of(1);
    }
    h2 p = __builtin_amdgcn_cvt_pkrtz(va, vb);
    px[id] = __builtin_bit_cast(unsigned, p);
}

// ---- weight transform: w[oc][ic][3][3] f32 -> block-contiguous packed f16:
// wt[((oc>>2)*ICP*9 + icp*9 + kk)*4 + (oc&3)], pair over ic = 2icp, 2icp+1 ----
template <int CIN, int COUT>
__global__ __launch_bounds__(256) void wtr2_kernel(const float* __restrict__ w,
                                                   unsigned* __restrict__ wt) {
    constexpr int ICP = (CIN + 1) / 2;
    const int L = ICP * 9 * COUT;
    const int id = blockIdx.x * 256 + threadIdx.x;
    if (id >= L) return;
    const float* src = w + (size_t)blockIdx.y * COUT * CIN * 9;
    unsigned* dst = wt + (size_t)blockIdx.y * L;
    const int oc = id % COUT;
    const int t = id / COUT;
    const int kk = t % 9, icp = t / 9;
    const int ic0 = icp * 2;
    const float a = src[(oc * CIN + ic0) * 9 + kk];
    const float b = (ic0 + 1 < CIN) ? src[(oc * CIN + ic0 + 1) * 9 + kk] : 0.f;
    h2 p = __builtin_amdgcn_cvt_pkrtz(a, b);
    dst[((oc >> 2) * ICP * 9 + icp * 9 + kk) * 4 + (oc & 3)] =
        __builtin_bit_cast(unsigned, p);
}

// ---- adder layer ----
// Packed input Pin: [b][ICP][50][64] u32 (zero halo). block = 192 thr = 3 waves;
// tile 4 rows x 48 cols x 4 oc. grid = (12, COUT/4, 4).
template <int ICP, int COUT, int MODE>
__global__ __launch_bounds__(192) void adder_kernel(const unsigned* __restrict__ Pin,
                                                    const unsigned* __restrict__ wt,
                                                    const float* __restrict__ res,
                                                    float* __restrict__ outf,
                                                    unsigned* __restrict__ outp) {
    constexpr int ICPC = (ICP < 8) ? ICP : 8;
    constexpr int NCH = ICP / ICPC;
    __shared__ unsigned s_in[ICPC][6][80];  // row stride 80: 2-way banks = free

    const int tid = threadIdx.x;
    const int wv = tid >> 6, lane = tid & 63;
    const int ly = lane >> 4, lx = (lane & 15) + wv * 16;

    const int y0 = blockIdx.x * 4;
    const int ocb = blockIdx.y;
    const int b = blockIdx.z;
    const int y = y0 + ly, x = lx;
    const int oc0 = ocb * 4;

    const unsigned* wb = wt + (size_t)ocb * ICP * 36;  // block-contiguous weights

    const int obase = ((b * COUT + oc0) * 48 + y) * 48 + x;
    float rsv[4] = {0.f, 0.f, 0.f, 0.f};
    if (MODE == M_RES || MODE == M_ADD) {
#pragma unroll
        for (int o = 0; o < 4; ++o) rsv[o] = res[obase + o * 2304];
    }

    // staging geometry: col = tid&63 (valid < 50), rg = tid>>6 covers rows rg, rg+3
    const int col = tid & 63, rg = tid >> 6;
    const unsigned* pbase = Pin + ((size_t)b * ICP * 50 + y0) * 64 + col;

    float acc0 = 0.f, acc1 = 0.f, acc2 = 0.f, acc3 = 0.f;

    for (int ch = 0; ch < NCH; ++ch) {
        const unsigned* p = pbase + (size_t)ch * ICPC * 3200;
        if (col < 50) {
#pragma unroll
            for (int icp = 0; icp < ICPC; ++icp) {
                s_in[icp][rg][col] = p[icp * 3200 + rg * 64];
                s_in[icp][rg + 3][col] = p[icp * 3200 + (rg + 3) * 64];
            }
        }
        __syncthreads();

#pragma unroll
        for (int icp = 0; icp < ICPC; ++icp) {
            unsigned f[3][3];
#pragma unroll
            for (int dy = 0; dy < 3; ++dy)
#pragma unroll
                for (int dx = 0; dx < 3; ++dx) f[dy][dx] = s_in[icp][ly + dy][lx + dx];
            const uint4* wq = (const uint4*)(wb + (ch * ICPC + icp) * 36);
#pragma unroll
            for (int kk = 0; kk < 9; ++kk) {
                const uint4 w4 = wq[kk];  // uniform address -> scalar load
                const h2 fv = __builtin_bit_cast(h2, f[kk / 3][kk % 3]);
                const unsigned AM = 0x7fff7fffu;
                {
                    h2 d = fv - __builtin_bit_cast(h2, w4.x);
                    acc0 = fdot2_acc(__builtin_bit_cast(unsigned, d) & AM, acc0);
                }
                {
                    h2 d = fv - __builtin_bit_cast(h2, w4.y);
                    acc1 = fdot2_acc(__builtin_bit_cast(unsigned, d) & AM, acc1);
                }
                {
                    h2 d = fv - __builtin_bit_cast(h2, w4.z);
                    acc2 = fdot2_acc(__builtin_bit_cast(unsigned, d) & AM, acc2);
                }
                {
                    h2 d = fv - __builtin_bit_cast(h2, w4.w);
                    acc3 = fdot2_acc(__builtin_bit_cast(unsigned, d) & AM, acc3);
                }
            }
        }
        if (ch + 1 < NCH) __syncthreads();
    }

    // ---- epilogue ----
    float v[4] = {acc0, acc1, acc2, acc3};
#pragma unroll
    for (int o = 0; o < 4; ++o) {
        if (MODE == M_RELU) v[o] = fmaxf(v[o], 0.f);
        if (MODE == M_RES) v[o] = rsv[o] + 0.1f * v[o];
        if (MODE == M_ADD) v[o] = rsv[o] + v[o];
    }
    if (MODE == M_PS) {
        // pixel-shuffle r=2 into f32 ps: plane ocb, (2y+o>>1, 2x+o&1)
#pragma unroll
        for (int o = 0; o < 4; ++o) {
            const int idx = ((b * 64 + ocb) * 96 + 2 * y + (o >> 1)) * 96 + 2 * x + (o & 1);
            outf[idx] = v[o];
        }
    } else {
        if (MODE == M_HEAD || MODE == M_RES) {
#pragma unroll
            for (int o = 0; o < 4; ++o) outf[obase + o * 2304] = v[o];
        }
        // packed output (all non-PS modes): planes oc0/2, oc0/2+1
        h2 p01 = __builtin_amdgcn_cvt_pkrtz(v[0], v[1]);
        h2 p23 = __builtin_amdgcn_cvt_pkrtz(v[2], v[3]);
        const int pidx = ((b * (COUT / 2) + (oc0 >> 1)) * 50 + (y + 1)) * 64 + (x + 1);
        outp[pidx] = __builtin_bit_cast(unsigned, p01);
        outp[pidx + 3200] = __builtin_bit_cast(unsigned, p23);
    }
}

// ---- tail: conv 64->3 over ps[4][64][96][96], ic split in 4 quarters ----
__global__ __launch_bounds__(256) void tail_kernel(const float* __restrict__ ps,
                                                   const float* __restrict__ tw,
                                                   const float* __restrict__ tb,
                                                   float* __restrict__ out) {
    __shared__ float s_w[432];  // [ic16*9+kk][oc], this quarter
    const int tid = threadIdx.x;
    const int icq = blockIdx.y;
    for (int i = tid; i < 432; i += 256) {
        const int ic16 = i / 27, r = i % 27, kk = r / 3, oc = r % 3;
        s_w[(ic16 * 9 + kk) * 3 + oc] = tw[((oc * 64) + icq * 16 + ic16) * 9 + kk];
    }
    __syncthreads();

    const int gid = blockIdx.x * 256 + tid;  // 36864 px
    const int b = gid / 9216;
    const int p = gid % 9216;
    const int Y = p / 96, X = p % 96;

    float a0 = 0.f, a1 = 0.f, a2 = 0.f;
    if (icq == 0) {
        a0 = tb[0] + mean_of(0);
        a1 = tb[1] + mean_of(1);
        a2 = tb[2] + mean_of(2);
    }
    const float* base = ps + ((size_t)b * 64 + icq * 16) * 9216;
    for (int ic = 0; ic < 16; ++ic) {
        const float* bp = base + ic * 9216;
#pragma unroll
        for (int kk = 0; kk < 9; ++kk) {
            const int yy = Y + kk / 3 - 1, xx = X + kk % 3 - 1;
            float fv = 0.f;
            if ((unsigned)yy < 96u && (unsigned)xx < 96u) fv = bp[yy * 96 + xx];
            const float* wr = &s_w[(ic * 9 + kk) * 3];
            a0 += fv * wr[0];
            a1 += fv * wr[1];
            a2 += fv * wr[2];
        }
    }
    atomicAdd(&out[((b * 3 + 0) * 96 + Y) * 96 + X], a0);
    atomicAdd(&out[((b * 3 + 1) * 96 + Y) * 96 + X], a1);
    atomicAdd(&out[((b * 3 + 2) * 96 + Y) * 96 + X], a2);
}

extern "C" void kernel_launch(void* const* d_in, const int* in_sizes, int n_in,
                              void* d_out, int out_size, void* d_ws, size_t ws_size,
                              hipStream_t stream) {
    const float* x      = (const float*)d_in[0];
    const float* head_w = (const float*)d_in[1];
    const float* rb_w1  = (const float*)d_in[2];
    const float* rb_w2  = (const float*)d_in[3];
    const float* body_w = (const float*)d_in[4];
    const float* up_w   = (const float*)d_in[5];
    const float* tail_w = (const float*)d_in[6];
    const float* tail_b = (const float*)d_in[7];
    float* out = (float*)d_out;

    // ws layout. f32 region (4S floats): s0, sA, sB + ps(4S) overlay.
    constexpr int S = 589824;        // 4*64*48*48
    constexpr int PK = 409600;       // one packed buffer: 4*32*50*64 u32
    float* ws = (float*)d_ws;
    float* s0 = ws;          // h (f32)
    float* sA = ws + 1 * S;
    float* sB = ws + 2 * S;
    float* ps = ws;          // 4S f32, overlays s0..sB at up-time (all dead)
    unsigned* pkR = (unsigned*)(ws + 4 * S);  // packed region start
    unsigned* pk_h = pkR;                     // head out; reused as pk_s4
    unsigned* pk_r = pkR + 1 * PK;
    unsigned* pk_bA = pkR + 2 * PK;
    unsigned* pk_bB = pkR + 3 * PK;
    unsigned* px = pkR + 4 * PK;              // 4*2*3200 = 25600
    unsigned* wtH = px + 25600;               // 1152
    unsigned* wt1 = wtH + 1152;               // 8 x 18432
    unsigned* wt2 = wt1 + 8 * 18432;
    unsigned* wtB = wt2 + 8 * 18432;          // 18432
    unsigned* wtU = wtB + 18432;              // 73728

    // ---- zero packed buffers (halo correctness) + out (tail atomics) ----
    zero_kernel<<<dim3(1024), dim3(256), 0, stream>>>((uint4*)pkR, 4 * PK / 4);
    zero_kernel<<<dim3(108), dim3(256), 0, stream>>>((uint4*)out, out_size / 4);
    packx_kernel<<<dim3(100), dim3(256), 0, stream>>>(x, px);

    wtr2_kernel<3, 64><<<dim3(5, 1), 256, 0, stream>>>(head_w, wtH);
    wtr2_kernel<64, 64><<<dim3(72, 8), 256, 0, stream>>>(rb_w1, wt1);
    wtr2_kernel<64, 64><<<dim3(72, 8), 256, 0, stream>>>(rb_w2, wt2);
    wtr2_kernel<64, 64><<<dim3(72, 1), 256, 0, stream>>>(body_w, wtB);
    wtr2_kernel<64, 256><<<dim3(288, 1), 256, 0, stream>>>(up_w, wtU);

    const dim3 blk(192);
    const dim3 gmid(12, 16, 4);  // 768 blocks = exactly 3/CU

    // head: f32 h -> s0, packed -> pk_h
    adder_kernel<2, 64, M_HEAD><<<gmid, blk, 0, stream>>>(px, wtH, nullptr, s0, pk_h);

    const unsigned* pk_cur = pk_h;
    const float* f_cur = s0;
    for (int k = 0; k < 8; ++k) {
        adder_kernel<32, 64, M_RELU><<<gmid, blk, 0, stream>>>(pk_cur, wt1 + k * 18432,
                                                               nullptr, nullptr, pk_r);
        float* f_nxt = (k & 1) ? sB : sA;
        unsigned* pk_nxt = (k & 1) ? pk_bB : pk_bA;
        adder_kernel<32, 64, M_RES><<<gmid, blk, 0, stream>>>(pk_r, wt2 + k * 18432,
                                                              f_cur, f_nxt, pk_nxt);
        f_cur = f_nxt;
        pk_cur = pk_nxt;
    }
    // body + global skip: pk_s4 (= pk_h storage) = h + body(b)
    adder_kernel<32, 64, M_ADD><<<gmid, blk, 0, stream>>>(pk_cur, wtB, s0, nullptr, pk_h);
    // up (COUT=256) with fused pixel-shuffle into f32 ps
    adder_kernel<32, 256, M_PS><<<dim3(12, 64, 4), blk, 0, stream>>>(pk_h, wtU, nullptr,
                                                                     ps, nullptr);
    // tail conv, 4 ic-quarters, atomic accumulate (+bias+mean on quarter 0)
    tail_kernel<<<dim3(144, 4), dim3(256), 0, stream>>>(ps, tail_w, tail_b, out);
}

// Round 7
// 549.468 us; speedup vs baseline: 34.4398x; 1.4979x over previous
//
#include <hip/hip_runtime.h>

// AdderNet-EDSR on MI355X. L1-dist has no matmul form -> VALU/LDS-bound.
// v7: split-K occupancy doubling. Waves/layer were pinned at 2304 (9/CU) by
// outputs/(64*4accs); split ic across two 3-wave groups in a 384-thr block
// (group0: icp 0..15, group1: icp 16..31, same spatial tile, LDS reduce at
// the end) -> 4608 waves = 18/CU at UNCHANGED per-output VALU + LDS cost.
// Keeps v6's: persistent packed-f16 activations w/ zero halo, s_load weights
// (readfirstlane'd group idx keeps them scalar), fdot2 1.5 inst/pair.

enum { M_PLAIN = 0, M_RELU = 1, M_RES = 2, M_ADD = 3, M_PS = 4, M_HEAD = 5 };

typedef __fp16 h2 __attribute__((ext_vector_type(2)));

__device__ __forceinline__ float mean_of(int c) {
    return c == 0 ? 0.4488f : (c == 1 ? 0.4371f : 0.404f);
}

__device__ __forceinline__ float fdot2_acc(unsigned u, float acc) {
    const h2 mh = {(__fp16)-1.0f, (__fp16)-1.0f};
#if __has_builtin(__builtin_amdgcn_fdot2)
    return __builtin_amdgcn_fdot2(__builtin_bit_cast(h2, u), mh, acc, false);
#else
    const unsigned MONES = 0xbc00bc00u;
    asm("v_dot2_f32_f16 %0, %1, %2, %0" : "+v"(acc) : "v"(u), "v"(MONES));
    return acc;
#endif
}

// ---- zero helper (grid-stride uint4) ----
__global__ __launch_bounds__(256) void zero_kernel(uint4* __restrict__ p, int n4) {
    const uint4 z = {0u, 0u, 0u, 0u};
    for (int i = blockIdx.x * 256 + threadIdx.x; i < n4; i += gridDim.x * 256)
        p[i] = z;
}

// ---- pack x - mean into px[b][icp=2][50][64] (halo included = 0) ----
__global__ __launch_bounds__(256) void packx_kernel(const float* __restrict__ x,
                                                    unsigned* __restrict__ px) {
    const int id = blockIdx.x * 256 + threadIdx.x;  // 25600
    if (id >= 25600) return;
    const int b = id / 6400, r = id % 6400;
    const int icp = r / 3200, r2 = r % 3200;
    const int yy = r2 / 64, xx = r2 % 64;
    const int y = yy - 1, gx = xx - 1;
    float va = 0.f, vb = 0.f;
    if ((unsigned)y < 48u && (unsigned)gx < 48u) {
        va = x[((b * 3 + 2 * icp) * 48 + y) * 48 + gx] - mean_of(2 * icp);
        if (icp == 0) vb = x[((b * 3 + 1) * 48 + y) * 48 + gx] - mean_of(1);
    }
    h2 p = __builtin_amdgcn_cvt_pkrtz(va, vb);
    px[id] = __builtin_bit_cast(unsigned, p);
}

// ---- weight transform: w[oc][ic][3][3] f32 -> block-contiguous packed f16:
// wt[((oc>>2)*ICP*9 + icp*9 + kk)*4 + (oc&3)] ----
template <int CIN, int COUT>
__global__ __launch_bounds__(256) void wtr2_kernel(const float* __restrict__ w,
                                                   unsigned* __restrict__ wt) {
    constexpr int ICP = (CIN + 1) / 2;
    const int L = ICP * 9 * COUT;
    const int id = blockIdx.x * 256 + threadIdx.x;
    if (id >= L) return;
    const float* src = w + (size_t)blockIdx.y * COUT * CIN * 9;
    unsigned* dst = wt + (size_t)blockIdx.y * L;
    const int oc = id % COUT;
    const int t = id / COUT;
    const int kk = t % 9, icp = t / 9;
    const int ic0 = icp * 2;
    const float a = src[(oc * CIN + ic0) * 9 + kk];
    const float b = (ic0 + 1 < CIN) ? src[(oc * CIN + ic0 + 1) * 9 + kk] : 0.f;
    h2 p = __builtin_amdgcn_cvt_pkrtz(a, b);
    dst[((oc >> 2) * ICP * 9 + icp * 9 + kk) * 4 + (oc & 3)] =
        __builtin_bit_cast(unsigned, p);
}

// ---- adder layer, split-K 384-thr ----
// Pin: [b][ICP][50][64] u32 (zero halo). 6 waves: waves 0-2 group0 (low icps),
// 3-5 group1 (high icps); both cover the same 4x48 tile x 4 oc. LDS reduce.
// grid = (12, COUT/4, 4).
template <int ICP, int COUT, int MODE>
__global__ __launch_bounds__(384) void adder_kernel(const unsigned* __restrict__ Pin,
                                                    const unsigned* __restrict__ wt,
                                                    const float* __restrict__ res,
                                                    float* __restrict__ outf,
                                                    unsigned* __restrict__ outp) {
    constexpr int GICP = ICP / 2;                  // icps per group
    constexpr int SICP = (GICP < 8) ? GICP : 8;    // per group per super-chunk
    constexpr int NSC = GICP / SICP;               // super-chunks
    __shared__ unsigned s_in[2 * SICP][6][80];     // stride 80 = 16 mod 32: 2-way free

    const int tid = threadIdx.x;
    const int w = __builtin_amdgcn_readfirstlane(tid) >> 6;  // wave id 0..5 (SGPR)
    const int g = (w >= 3) ? 1 : 0;                          // group (SGPR)
    const int wg = w - g * 3;                                // wave within group
    const int lane = tid & 63;
    const int ly = lane >> 4, lx = (lane & 15) + wg * 16;

    const int y0 = blockIdx.x * 4;
    const int ocb = blockIdx.y;
    const int b = blockIdx.z;
    const int y = y0 + ly, x = lx;
    const int oc0 = ocb * 4;

    const unsigned* wb = wt + (size_t)ocb * ICP * 36;

    const int obase = ((b * COUT + oc0) * 48 + y) * 48 + x;
    float rsv[4] = {0.f, 0.f, 0.f, 0.f};
    if ((MODE == M_RES || MODE == M_ADD) && tid < 192) {
#pragma unroll
        for (int o = 0; o < 4; ++o) rsv[o] = res[obase + o * 2304];
    }

    // staging: col = tid&63 (<50), row rg = tid>>6 (0..5) -> exactly 6 rows
    const int col = tid & 63, rg = tid >> 6;
    const unsigned* pbase = Pin + ((size_t)b * ICP * 50 + y0 + rg) * 64 + col;

    float acc0 = 0.f, acc1 = 0.f, acc2 = 0.f, acc3 = 0.f;

    for (int sc = 0; sc < NSC; ++sc) {
        const unsigned* p = pbase + (size_t)sc * (2 * SICP) * 3200;
        if (col < 50) {
#pragma unroll
            for (int j = 0; j < 2 * SICP; ++j) s_in[j][rg][col] = p[j * 3200];
        }
        __syncthreads();

#pragma unroll
        for (int jl = 0; jl < SICP; ++jl) {
            const int li = g * SICP + jl;                   // LDS plane
            unsigned f[3][3];
#pragma unroll
            for (int dy = 0; dy < 3; ++dy)
#pragma unroll
                for (int dx = 0; dx < 3; ++dx) f[dy][dx] = s_in[li][ly + dy][lx + dx];
            const uint4* wq =
                (const uint4*)(wb + (size_t)(sc * 2 * SICP + g * SICP + jl) * 36);
#pragma unroll
            for (int kk = 0; kk < 9; ++kk) {
                const uint4 w4 = wq[kk];  // scalar load (uniform addr)
                const h2 fv = __builtin_bit_cast(h2, f[kk / 3][kk % 3]);
                const unsigned AM = 0x7fff7fffu;
                {
                    h2 d = fv - __builtin_bit_cast(h2, w4.x);
                    acc0 = fdot2_acc(__builtin_bit_cast(unsigned, d) & AM, acc0);
                }
                {
                    h2 d = fv - __builtin_bit_cast(h2, w4.y);
                    acc1 = fdot2_acc(__builtin_bit_cast(unsigned, d) & AM, acc1);
                }
                {
                    h2 d = fv - __builtin_bit_cast(h2, w4.z);
                    acc2 = fdot2_acc(__builtin_bit_cast(unsigned, d) & AM, acc2);
                }
                {
                    h2 d = fv - __builtin_bit_cast(h2, w4.w);
                    acc3 = fdot2_acc(__builtin_bit_cast(unsigned, d) & AM, acc3);
                }
            }
        }
        __syncthreads();
    }

    // ---- cross-group reduce (reuse s_in as scratch) ----
    float* s_red = (float*)&s_in[0][0][0];
    if (tid >= 192) {
        float4 a4 = {acc0, acc1, acc2, acc3};
        *(float4*)&s_red[(tid - 192) * 4] = a4;
    }
    __syncthreads();
    if (tid >= 192) return;
    {
        const float4 a4 = *(const float4*)&s_red[tid * 4];
        acc0 += a4.x;
        acc1 += a4.y;
        acc2 += a4.z;
        acc3 += a4.w;
    }

    // ---- epilogue (192 threads) ----
    float v[4] = {acc0, acc1, acc2, acc3};
#pragma unroll
    for (int o = 0; o < 4; ++o) {
        if (MODE == M_RELU) v[o] = fmaxf(v[o], 0.f);
        if (MODE == M_RES) v[o] = rsv[o] + 0.1f * v[o];
        if (MODE == M_ADD) v[o] = rsv[o] + v[o];
    }
    if (MODE == M_PS) {
#pragma unroll
        for (int o = 0; o < 4; ++o) {
            const int idx = ((b * 64 + ocb) * 96 + 2 * y + (o >> 1)) * 96 + 2 * x + (o & 1);
            outf[idx] = v[o];
        }
    } else {
        if (MODE == M_HEAD || MODE == M_RES) {
#pragma unroll
            for (int o = 0; o < 4; ++o) outf[obase + o * 2304] = v[o];
        }
        h2 p01 = __builtin_amdgcn_cvt_pkrtz(v[0], v[1]);
        h2 p23 = __builtin_amdgcn_cvt_pkrtz(v[2], v[3]);
        const int pidx = ((b * (COUT / 2) + (oc0 >> 1)) * 50 + (y + 1)) * 64 + (x + 1);
        outp[pidx] = __builtin_bit_cast(unsigned, p01);
        outp[pidx + 3200] = __builtin_bit_cast(unsigned, p23);
    }
}

// ---- tail: conv 64->3 over ps[4][64][96][96], ic split in 4 quarters ----
__global__ __launch_bounds__(256) void tail_kernel(const float* __restrict__ ps,
                                                   const float* __restrict__ tw,
                                                   const float* __restrict__ tb,
                                                   float* __restrict__ out) {
    __shared__ float s_w[432];
    const int tid = threadIdx.x;
    const int icq = blockIdx.y;
    for (int i = tid; i < 432; i += 256) {
        const int ic16 = i / 27, r = i % 27, kk = r / 3, oc = r % 3;
        s_w[(ic16 * 9 + kk) * 3 + oc] = tw[((oc * 64) + icq * 16 + ic16) * 9 + kk];
    }
    __syncthreads();

    const int gid = blockIdx.x * 256 + tid;
    const int b = gid / 9216;
    const int p = gid % 9216;
    const int Y = p / 96, X = p % 96;

    float a0 = 0.f, a1 = 0.f, a2 = 0.f;
    if (icq == 0) {
        a0 = tb[0] + mean_of(0);
        a1 = tb[1] + mean_of(1);
        a2 = tb[2] + mean_of(2);
    }
    const float* base = ps + ((size_t)b * 64 + icq * 16) * 9216;
    for (int ic = 0; ic < 16; ++ic) {
        const float* bp = base + ic * 9216;
#pragma unroll
        for (int kk = 0; kk < 9; ++kk) {
            const int yy = Y + kk / 3 - 1, xx = X + kk % 3 - 1;
            float fv = 0.f;
            if ((unsigned)yy < 96u && (unsigned)xx < 96u) fv = bp[yy * 96 + xx];
            const float* wr = &s_w[(ic * 9 + kk) * 3];
            a0 += fv * wr[0];
            a1 += fv * wr[1];
            a2 += fv * wr[2];
        }
    }
    atomicAdd(&out[((b * 3 + 0) * 96 + Y) * 96 + X], a0);
    atomicAdd(&out[((b * 3 + 1) * 96 + Y) * 96 + X], a1);
    atomicAdd(&out[((b * 3 + 2) * 96 + Y) * 96 + X], a2);
}

extern "C" void kernel_launch(void* const* d_in, const int* in_sizes, int n_in,
                              void* d_out, int out_size, void* d_ws, size_t ws_size,
                              hipStream_t stream) {
    const float* x      = (const float*)d_in[0];
    const float* head_w = (const float*)d_in[1];
    const float* rb_w1  = (const float*)d_in[2];
    const float* rb_w2  = (const float*)d_in[3];
    const float* body_w = (const float*)d_in[4];
    const float* up_w   = (const float*)d_in[5];
    const float* tail_w = (const float*)d_in[6];
    const float* tail_b = (const float*)d_in[7];
    float* out = (float*)d_out;

    constexpr int S = 589824;   // 4*64*48*48 (f32 plane set)
    constexpr int PK = 409600;  // packed buffer: 4*32*50*64 u32
    float* ws = (float*)d_ws;
    float* s0 = ws;          // h (f32)
    float* sA = ws + 1 * S;
    float* sB = ws + 2 * S;
    float* ps = ws;          // 4S f32 overlay (s0..sB dead at up-time)
    unsigned* pkR = (unsigned*)(ws + 4 * S);
    unsigned* pk_h = pkR;
    unsigned* pk_r = pkR + 1 * PK;
    unsigned* pk_bA = pkR + 2 * PK;
    unsigned* pk_bB = pkR + 3 * PK;
    unsigned* px = pkR + 4 * PK;   // 25600
    unsigned* wtH = px + 25600;    // 1152
    unsigned* wt1 = wtH + 1152;    // 8 x 18432
    unsigned* wt2 = wt1 + 8 * 18432;
    unsigned* wtB = wt2 + 8 * 18432;
    unsigned* wtU = wtB + 18432;   // 73728

    zero_kernel<<<dim3(1024), dim3(256), 0, stream>>>((uint4*)pkR, 4 * PK / 4);
    zero_kernel<<<dim3(108), dim3(256), 0, stream>>>((uint4*)out, out_size / 4);
    packx_kernel<<<dim3(100), dim3(256), 0, stream>>>(x, px);

    wtr2_kernel<3, 64><<<dim3(5, 1), 256, 0, stream>>>(head_w, wtH);
    wtr2_kernel<64, 64><<<dim3(72, 8), 256, 0, stream>>>(rb_w1, wt1);
    wtr2_kernel<64, 64><<<dim3(72, 8), 256, 0, stream>>>(rb_w2, wt2);
    wtr2_kernel<64, 64><<<dim3(72, 1), 256, 0, stream>>>(body_w, wtB);
    wtr2_kernel<64, 256><<<dim3(288, 1), 256, 0, stream>>>(up_w, wtU);

    const dim3 blk(384);
    const dim3 gmid(12, 16, 4);  // 768 blocks x 6 waves = 18 waves/CU

    adder_kernel<2, 64, M_HEAD><<<gmid, blk, 0, stream>>>(px, wtH, nullptr, s0, pk_h);

    const unsigned* pk_cur = pk_h;
    const float* f_cur = s0;
    for (int k = 0; k < 8; ++k) {
        adder_kernel<32, 64, M_RELU><<<gmid, blk, 0, stream>>>(pk_cur, wt1 + k * 18432,
                                                               nullptr, nullptr, pk_r);
        float* f_nxt = (k & 1) ? sB : sA;
        unsigned* pk_nxt = (k & 1) ? pk_bB : pk_bA;
        adder_kernel<32, 64, M_RES><<<gmid, blk, 0, stream>>>(pk_r, wt2 + k * 18432,
                                                              f_cur, f_nxt, pk_nxt);
        f_cur = f_nxt;
        pk_cur = pk_nxt;
    }
    adder_kernel<32, 64, M_ADD><<<gmid, blk, 0, stream>>>(pk_cur, wtB, s0, nullptr, pk_h);
    adder_kernel<32, 256, M_PS><<<dim3(12, 64, 4), blk, 0, stream>>>(pk_h, wtU, nullptr,
                                                                     ps, nullptr);
    tail_kernel<<<dim3(144, 4), dim3(256), 0, stream>>>(ps, tail_w, tail_b, out);
}

// Round 8
// 204.327 us; speedup vs baseline: 92.6139x; 2.6892x over previous
//
#include <hip/hip_runtime.h>

// AdderNet-EDSR on MI355X. v8: ALGORITHMIC COLLAPSE.
// adder2d output = -Sum|.| <= 0 always => relu(adder2d(b,w1)) == 0 exactly
// => rb1 never matters; rb2 sees an all-zero input (pad also 0) so its output
// is the constant -Sum|w2[oc]| at every pixel. Each residual block is just
// b += 0.1 * C_k[oc]. Network = head -> +shift[oc] -> body -> +h -> up -> PS
// -> tail: only 3 real adder layers (head/body/up). Kernel machinery from v7:
// split-K 384-thr blocks (2 groups x 3 waves), packed-f16 activations with
// zero halo, s_load weights, fdot2 (1.5 inst/pair), stride-80 LDS (2-way free).

enum { M_ADD = 3, M_PS = 4, M_HEAD = 5 };

typedef __fp16 h2 __attribute__((ext_vector_type(2)));

__device__ __forceinline__ float mean_of(int c) {
    return c == 0 ? 0.4488f : (c == 1 ? 0.4371f : 0.404f);
}

__device__ __forceinline__ float fdot2_acc(unsigned u, float acc) {
    const h2 mh = {(__fp16)-1.0f, (__fp16)-1.0f};
#if __has_builtin(__builtin_amdgcn_fdot2)
    return __builtin_amdgcn_fdot2(__builtin_bit_cast(h2, u), mh, acc, false);
#else
    const unsigned MONES = 0xbc00bc00u;
    asm("v_dot2_f32_f16 %0, %1, %2, %0" : "+v"(acc) : "v"(u), "v"(MONES));
    return acc;
#endif
}

// ---- zero helper (grid-stride uint4) ----
__global__ __launch_bounds__(256) void zero_kernel(uint4* __restrict__ p, int n4) {
    const uint4 z = {0u, 0u, 0u, 0u};
    for (int i = blockIdx.x * 256 + threadIdx.x; i < n4; i += gridDim.x * 256)
        p[i] = z;
}

// ---- pack x - mean into px[b][icp=2][50][64] (halo = 0) ----
__global__ __launch_bounds__(256) void packx_kernel(const float* __restrict__ x,
                                                    unsigned* __restrict__ px) {
    const int id = blockIdx.x * 256 + threadIdx.x;  // 25600
    if (id >= 25600) return;
    const int b = id / 6400, r = id % 6400;
    const int icp = r / 3200, r2 = r % 3200;
    const int yy = r2 / 64, xx = r2 % 64;
    const int y = yy - 1, gx = xx - 1;
    float va = 0.f, vb = 0.f;
    if ((unsigned)y < 48u && (unsigned)gx < 48u) {
        va = x[((b * 3 + 2 * icp) * 48 + y) * 48 + gx] - mean_of(2 * icp);
        if (icp == 0) vb = x[((b * 3 + 1) * 48 + y) * 48 + gx] - mean_of(1);
    }
    h2 p = __builtin_amdgcn_cvt_pkrtz(va, vb);
    px[id] = __builtin_bit_cast(unsigned, p);
}

// ---- weight transform: w[oc][ic][3][3] f32 -> block-contiguous packed f16 ----
template <int CIN, int COUT>
__global__ __launch_bounds__(256) void wtr2_kernel(const float* __restrict__ w,
                                                   unsigned* __restrict__ wt) {
    constexpr int ICP = (CIN + 1) / 2;
    const int L = ICP * 9 * COUT;
    const int id = blockIdx.x * 256 + threadIdx.x;
    if (id >= L) return;
    const int oc = id % COUT;
    const int t = id / COUT;
    const int kk = t % 9, icp = t / 9;
    const int ic0 = icp * 2;
    const float a = w[(oc * CIN + ic0) * 9 + kk];
    const float b = (ic0 + 1 < CIN) ? w[(oc * CIN + ic0 + 1) * 9 + kk] : 0.f;
    h2 p = __builtin_amdgcn_cvt_pkrtz(a, b);
    wt[((oc >> 2) * ICP * 9 + icp * 9 + kk) * 4 + (oc & 3)] =
        __builtin_bit_cast(unsigned, p);
}

// ---- residual-chain collapse: shift[oc] = -0.1 * Sum_k Sum_{ic,kk}|rb_w2| ----
__global__ __launch_bounds__(256) void shift_kernel(const float* __restrict__ w2,
                                                    float* __restrict__ shift) {
    __shared__ float s_red[256];
    const int oc = blockIdx.x;
    const int tid = threadIdx.x;
    float s = 0.f;
    for (int e = tid; e < 4608; e += 256) {
        const int k = e / 576, j = e % 576;
        s += fabsf(w2[k * 36864 + oc * 576 + j]);
    }
    s_red[tid] = s;
    __syncthreads();
    for (int st = 128; st > 0; st >>= 1) {
        if (tid < st) s_red[tid] += s_red[tid + st];
        __syncthreads();
    }
    if (tid == 0) shift[oc] = -0.1f * s_red[0];
}

// ---- adder layer, split-K 384-thr (v7 structure) ----
// Pin: [b][ICP][50][64] u32 zero-halo. grid = (12, COUT/4, 4).
template <int ICP, int COUT, int MODE>
__global__ __launch_bounds__(384) void adder_kernel(const unsigned* __restrict__ Pin,
                                                    const unsigned* __restrict__ wt,
                                                    const float* __restrict__ res,
                                                    const float* __restrict__ shp,
                                                    float* __restrict__ outf,
                                                    unsigned* __restrict__ outp) {
    constexpr int GICP = ICP / 2;
    constexpr int SICP = (GICP < 8) ? GICP : 8;
    constexpr int NSC = GICP / SICP;
    __shared__ unsigned s_in[2 * SICP][6][80];  // stride 80 == 16 mod 32: 2-way free

    const int tid = threadIdx.x;
    const int w = __builtin_amdgcn_readfirstlane(tid) >> 6;  // wave 0..5 (SGPR)
    const int g = (w >= 3) ? 1 : 0;
    const int wg = w - g * 3;
    const int lane = tid & 63;
    const int ly = lane >> 4, lx = (lane & 15) + wg * 16;

    const int y0 = blockIdx.x * 4;
    const int ocb = blockIdx.y;
    const int b = blockIdx.z;
    const int y = y0 + ly, x = lx;
    const int oc0 = ocb * 4;

    const unsigned* wb = wt + (size_t)ocb * ICP * 36;

    const int obase = ((b * COUT + oc0) * 48 + y) * 48 + x;
    float rsv[4] = {0.f, 0.f, 0.f, 0.f};
    if (MODE == M_ADD && tid < 192) {
#pragma unroll
        for (int o = 0; o < 4; ++o) rsv[o] = res[obase + o * 2304];
    }

    const int col = tid & 63, rg = tid >> 6;
    const unsigned* pbase = Pin + ((size_t)b * ICP * 50 + y0 + rg) * 64 + col;

    float acc0 = 0.f, acc1 = 0.f, acc2 = 0.f, acc3 = 0.f;

    for (int sc = 0; sc < NSC; ++sc) {
        const unsigned* p = pbase + (size_t)sc * (2 * SICP) * 3200;
        if (col < 50) {
#pragma unroll
            for (int j = 0; j < 2 * SICP; ++j) s_in[j][rg][col] = p[j * 3200];
        }
        __syncthreads();

#pragma unroll
        for (int jl = 0; jl < SICP; ++jl) {
            const int li = g * SICP + jl;
            unsigned f[3][3];
#pragma unroll
            for (int dy = 0; dy < 3; ++dy)
#pragma unroll
                for (int dx = 0; dx < 3; ++dx) f[dy][dx] = s_in[li][ly + dy][lx + dx];
            const uint4* wq =
                (const uint4*)(wb + (size_t)(sc * 2 * SICP + g * SICP + jl) * 36);
#pragma unroll
            for (int kk = 0; kk < 9; ++kk) {
                const uint4 w4 = wq[kk];  // uniform addr -> s_load
                const h2 fv = __builtin_bit_cast(h2, f[kk / 3][kk % 3]);
                const unsigned AM = 0x7fff7fffu;
                {
                    h2 d = fv - __builtin_bit_cast(h2, w4.x);
                    acc0 = fdot2_acc(__builtin_bit_cast(unsigned, d) & AM, acc0);
                }
                {
                    h2 d = fv - __builtin_bit_cast(h2, w4.y);
                    acc1 = fdot2_acc(__builtin_bit_cast(unsigned, d) & AM, acc1);
                }
                {
                    h2 d = fv - __builtin_bit_cast(h2, w4.z);
                    acc2 = fdot2_acc(__builtin_bit_cast(unsigned, d) & AM, acc2);
                }
                {
                    h2 d = fv - __builtin_bit_cast(h2, w4.w);
                    acc3 = fdot2_acc(__builtin_bit_cast(unsigned, d) & AM, acc3);
                }
            }
        }
        __syncthreads();
    }

    // ---- cross-group reduce (reuse s_in as scratch) ----
    float* s_red = (float*)&s_in[0][0][0];
    if (tid >= 192) {
        float4 a4 = {acc0, acc1, acc2, acc3};
        *(float4*)&s_red[(tid - 192) * 4] = a4;
    }
    __syncthreads();
    if (tid >= 192) return;
    {
        const float4 a4 = *(const float4*)&s_red[tid * 4];
        acc0 += a4.x;
        acc1 += a4.y;
        acc2 += a4.z;
        acc3 += a4.w;
    }

    // ---- epilogue (192 threads) ----
    float v[4] = {acc0, acc1, acc2, acc3};
    if (MODE == M_ADD) {
#pragma unroll
        for (int o = 0; o < 4; ++o) v[o] = rsv[o] + v[o];
    }
    if (MODE == M_PS) {
#pragma unroll
        for (int o = 0; o < 4; ++o) {
            const int idx = ((b * 64 + ocb) * 96 + 2 * y + (o >> 1)) * 96 + 2 * x + (o & 1);
            outf[idx] = v[o];
        }
    } else {
        if (MODE == M_HEAD) {
#pragma unroll
            for (int o = 0; o < 4; ++o) outf[obase + o * 2304] = v[o];  // f32 h
        }
        // packed output; head packs (h + shift[oc]) = body input
        float pv[4];
#pragma unroll
        for (int o = 0; o < 4; ++o)
            pv[o] = (MODE == M_HEAD) ? v[o] + shp[oc0 + o] : v[o];
        h2 p01 = __builtin_amdgcn_cvt_pkrtz(pv[0], pv[1]);
        h2 p23 = __builtin_amdgcn_cvt_pkrtz(pv[2], pv[3]);
        const int pidx = ((b * (COUT / 2) + (oc0 >> 1)) * 50 + (y + 1)) * 64 + (x + 1);
        outp[pidx] = __builtin_bit_cast(unsigned, p01);
        outp[pidx + 3200] = __builtin_bit_cast(unsigned, p23);
    }
}

// ---- tail: conv 64->3 over ps[4][64][96][96], ic in 4 quarters ----
__global__ __launch_bounds__(256) void tail_kernel(const float* __restrict__ ps,
                                                   const float* __restrict__ tw,
                                                   const float* __restrict__ tb,
                                                   float* __restrict__ out) {
    __shared__ float s_w[432];
    const int tid = threadIdx.x;
    const int icq = blockIdx.y;
    for (int i = tid; i < 432; i += 256) {
        const int ic16 = i / 27, r = i % 27, kk = r / 3, oc = r % 3;
        s_w[(ic16 * 9 + kk) * 3 + oc] = tw[((oc * 64) + icq * 16 + ic16) * 9 + kk];
    }
    __syncthreads();

    const int gid = blockIdx.x * 256 + tid;
    const int b = gid / 9216;
    const int p = gid % 9216;
    const int Y = p / 96, X = p % 96;

    float a0 = 0.f, a1 = 0.f, a2 = 0.f;
    if (icq == 0) {
        a0 = tb[0] + mean_of(0);
        a1 = tb[1] + mean_of(1);
        a2 = tb[2] + mean_of(2);
    }
    const float* base = ps + ((size_t)b * 64 + icq * 16) * 9216;
    for (int ic = 0; ic < 16; ++ic) {
        const float* bp = base + ic * 9216;
#pragma unroll
        for (int kk = 0; kk < 9; ++kk) {
            const int yy = Y + kk / 3 - 1, xx = X + kk % 3 - 1;
            float fv = 0.f;
            if ((unsigned)yy < 96u && (unsigned)xx < 96u) fv = bp[yy * 96 + xx];
            const float* wr = &s_w[(ic * 9 + kk) * 3];
            a0 += fv * wr[0];
            a1 += fv * wr[1];
            a2 += fv * wr[2];
        }
    }
    atomicAdd(&out[((b * 3 + 0) * 96 + Y) * 96 + X], a0);
    atomicAdd(&out[((b * 3 + 1) * 96 + Y) * 96 + X], a1);
    atomicAdd(&out[((b * 3 + 2) * 96 + Y) * 96 + X], a2);
}

extern "C" void kernel_launch(void* const* d_in, const int* in_sizes, int n_in,
                              void* d_out, int out_size, void* d_ws, size_t ws_size,
                              hipStream_t stream) {
    const float* x      = (const float*)d_in[0];
    const float* head_w = (const float*)d_in[1];
    const float* rb_w2  = (const float*)d_in[3];
    const float* body_w = (const float*)d_in[4];
    const float* up_w   = (const float*)d_in[5];
    const float* tail_w = (const float*)d_in[6];
    const float* tail_b = (const float*)d_in[7];
    float* out = (float*)d_out;

    constexpr int S = 589824;   // 4*64*48*48
    constexpr int PK = 409600;  // 4*32*50*64 u32
    float* ws = (float*)d_ws;
    float* s0 = ws;          // f32 h
    float* ps = ws;          // 4S f32, overlays s0 (h dead at up-time)
    unsigned* pk_hs = (unsigned*)(ws + 4 * S);  // packed (h + shift)
    unsigned* pk_res = pk_hs + PK;              // packed res = h + body
    unsigned* px = pk_res + PK;                 // 25600
    unsigned* wtH = px + 25600;                 // 1152
    unsigned* wtB = wtH + 1152;                 // 18432
    unsigned* wtU = wtB + 18432;                // 73728
    float* shift = (float*)(wtU + 73728);       // 64

    zero_kernel<<<dim3(512), dim3(256), 0, stream>>>((uint4*)pk_hs, 2 * PK / 4);
    zero_kernel<<<dim3(108), dim3(256), 0, stream>>>((uint4*)out, out_size / 4);
    packx_kernel<<<dim3(100), dim3(256), 0, stream>>>(x, px);

    wtr2_kernel<3, 64><<<dim3(5), 256, 0, stream>>>(head_w, wtH);
    wtr2_kernel<64, 64><<<dim3(72), 256, 0, stream>>>(body_w, wtB);
    wtr2_kernel<64, 256><<<dim3(288), 256, 0, stream>>>(up_w, wtU);
    shift_kernel<<<dim3(64), dim3(256), 0, stream>>>(rb_w2, shift);

    const dim3 blk(384);
    const dim3 g64(12, 16, 4);

    // head: f32 h -> s0, packed(h+shift) -> pk_hs
    adder_kernel<2, 64, M_HEAD><<<g64, blk, 0, stream>>>(px, wtH, nullptr, shift, s0,
                                                         pk_hs);
    // body: res = h + body(h+shift) -> packed pk_res
    adder_kernel<32, 64, M_ADD><<<g64, blk, 0, stream>>>(pk_hs, wtB, s0, nullptr,
                                                         nullptr, pk_res);
    // up (COUT=256) + fused pixel-shuffle -> f32 ps
    adder_kernel<32, 256, M_PS><<<dim3(12, 64, 4), blk, 0, stream>>>(
        pk_res, wtU, nullptr, nullptr, ps, nullptr);
    // tail conv (4 ic-quarters, atomic)
    tail_kernel<<<dim3(144, 4), dim3(256), 0, stream>>>(ps, tail_w, tail_b, out);
}

// Round 9
// 197.156 us; speedup vs baseline: 95.9826x; 1.0364x over previous
//
#include <hip/hip_runtime.h>

// AdderNet-EDSR on MI355X. v9 = v8 (algorithmic collapse: relu(adder)==0 =>
// residual chain is a per-channel constant shift; only head/body/up are real
// adder layers) + two kernel-level changes:
//  (1) up layer (COUT=256) computes 8 oc/thread -> LDS window reads per pair
//      halve (the up layer was 83us, ~40% of total; LDS-pipe floor 25->12.5us),
//      VALU per pair unchanged, grid (12,32,4)=1536 blocks (36 waves/CU).
//  (2) all setup work fused into ONE kernel (blockIdx-range branches):
//      11 dispatches -> 5 (launch gaps were ~30-50us of the 204).
// Machinery: split-K 384-thr blocks (2 groups x 3 waves), packed-f16
// activations with zero halo, s_load weights, fdot2 (1.5 inst/pair),
// stride-80 LDS (2-way bank = free).

enum { M_ADD = 3, M_PS = 4, M_HEAD = 5 };

typedef __fp16 h2 __attribute__((ext_vector_type(2)));

__device__ __forceinline__ float mean_of(int c) {
    return c == 0 ? 0.4488f : (c == 1 ? 0.4371f : 0.404f);
}

__device__ __forceinline__ float fdot2_acc(unsigned u, float acc) {
    const h2 mh = {(__fp16)-1.0f, (__fp16)-1.0f};
#if __has_builtin(__builtin_amdgcn_fdot2)
    return __builtin_amdgcn_fdot2(__builtin_bit_cast(h2, u), mh, acc, false);
#else
    const unsigned MONES = 0xbc00bc00u;
    asm("v_dot2_f32_f16 %0, %1, %2, %0" : "+v"(acc) : "v"(u), "v"(MONES));
    return acc;
#endif
}

// ---- fused setup: weight transforms (packed f16, block-contiguous), packx,
// shift reduction, zero pk buffers, zero out. One launch. ----
// blocks: [0,288) wtU | [288,360) wtB | [360,365) wtH | [365,465) packx |
//         [465,529) shift | [529,785) zero pk (grid-stride) | [785,893) zero out
__global__ __launch_bounds__(256) void setup_kernel(
    const float* __restrict__ x, const float* __restrict__ head_w,
    const float* __restrict__ rb_w2, const float* __restrict__ body_w,
    const float* __restrict__ up_w, unsigned* __restrict__ px,
    unsigned* __restrict__ wtH, unsigned* __restrict__ wtB,
    unsigned* __restrict__ wtU, float* __restrict__ shift,
    unsigned* __restrict__ pkz, float* __restrict__ out) {
    __shared__ float s_red[256];
    const int bx = blockIdx.x, tid = threadIdx.x;

    if (bx < 288) {  // up weights: CIN=64 ICP=32 COUT=256 OCPB=8
        const int id = bx * 256 + tid;  // L = 73728
        if (id < 73728) {
            const int oc = id % 256;
            const int t = id / 256;
            const int kk = t % 9, icp = t / 9;
            const float a = up_w[(oc * 64 + 2 * icp) * 9 + kk];
            const float b = up_w[(oc * 64 + 2 * icp + 1) * 9 + kk];
            h2 p = __builtin_amdgcn_cvt_pkrtz(a, b);
            wtU[((oc >> 3) * 288 + icp * 9 + kk) * 8 + (oc & 7)] =
                __builtin_bit_cast(unsigned, p);
        }
    } else if (bx < 360) {  // body weights: ICP=32 COUT=64 OCPB=4
        const int id = (bx - 288) * 256 + tid;  // L = 18432
        if (id < 18432) {
            const int oc = id % 64;
            const int t = id / 64;
            const int kk = t % 9, icp = t / 9;
            const float a = body_w[(oc * 64 + 2 * icp) * 9 + kk];
            const float b = body_w[(oc * 64 + 2 * icp + 1) * 9 + kk];
            h2 p = __builtin_amdgcn_cvt_pkrtz(a, b);
            wtB[((oc >> 2) * 288 + icp * 9 + kk) * 4 + (oc & 3)] =
                __builtin_bit_cast(unsigned, p);
        }
    } else if (bx < 365) {  // head weights: CIN=3 ICP=2 COUT=64 OCPB=4
        const int id = (bx - 360) * 256 + tid;  // L = 1152
        if (id < 1152) {
            const int oc = id % 64;
            const int t = id / 64;
            const int kk = t % 9, icp = t / 9;
            const float a = head_w[(oc * 3 + 2 * icp) * 9 + kk];
            const float b = (icp == 0) ? head_w[(oc * 3 + 1) * 9 + kk] : 0.f;
            h2 p = __builtin_amdgcn_cvt_pkrtz(a, b);
            wtH[((oc >> 2) * 18 + icp * 9 + kk) * 4 + (oc & 3)] =
                __builtin_bit_cast(unsigned, p);
        }
    } else if (bx < 465) {  // pack x - mean into px[b][2][50][64] (halo = 0)
        const int id = (bx - 365) * 256 + tid;  // 25600
        if (id < 25600) {
            const int b = id / 6400, r = id % 6400;
            const int icp = r / 3200, r2 = r % 3200;
            const int yy = r2 / 64, xx = r2 % 64;
            const int y = yy - 1, gx = xx - 1;
            float va = 0.f, vb = 0.f;
            if ((unsigned)y < 48u && (unsigned)gx < 48u) {
                va = x[((b * 3 + 2 * icp) * 48 + y) * 48 + gx] - mean_of(2 * icp);
                if (icp == 0) vb = x[((b * 3 + 1) * 48 + y) * 48 + gx] - mean_of(1);
            }
            h2 p = __builtin_amdgcn_cvt_pkrtz(va, vb);
            px[id] = __builtin_bit_cast(unsigned, p);
        }
    } else if (bx < 529) {  // shift[oc] = -0.1 * Sum_k Sum|rb_w2[k][oc]|
        const int oc = bx - 465;
        float s = 0.f;
        for (int e = tid; e < 4608; e += 256) {
            const int k = e / 576, j = e % 576;
            s += fabsf(rb_w2[k * 36864 + oc * 576 + j]);
        }
        s_red[tid] = s;
        __syncthreads();
        for (int st = 128; st > 0; st >>= 1) {
            if (tid < st) s_red[tid] += s_red[tid + st];
            __syncthreads();
        }
        if (tid == 0) shift[oc] = -0.1f * s_red[0];
    } else if (bx < 785) {  // zero both pk buffers (2*409600 u32 = 204800 uint4)
        const uint4 z = {0u, 0u, 0u, 0u};
        for (int i = (bx - 529) * 256 + tid; i < 204800; i += 256 * 256)
            ((uint4*)pkz)[i] = z;
    } else {  // zero out (tail atomics): 110592 f32 = 27648 uint4
        const int id = (bx - 785) * 256 + tid;
        const uint4 z = {0u, 0u, 0u, 0u};
        if (id < 27648) ((uint4*)out)[id] = z;
    }
}

// ---- adder layer, split-K 384-thr, OCPB oc per thread ----
// Pin: [b][ICP][50][64] u32 zero-halo. grid = (12, COUT/OCPB, 4).
template <int ICP, int COUT, int OCPB, int MODE>
__global__ __launch_bounds__(384) void adder_kernel(const unsigned* __restrict__ Pin,
                                                    const unsigned* __restrict__ wt,
                                                    const float* __restrict__ res,
                                                    const float* __restrict__ shp,
                                                    float* __restrict__ outf,
                                                    unsigned* __restrict__ outp) {
    constexpr int GICP = ICP / 2;
    constexpr int SICP = (GICP < 8) ? GICP : 8;
    constexpr int NSC = GICP / SICP;
    constexpr int NQ = OCPB / 4;
    __shared__ unsigned s_in[2 * SICP][6][80];  // stride 80 == 16 mod 32: 2-way free

    const int tid = threadIdx.x;
    const int w = __builtin_amdgcn_readfirstlane(tid) >> 6;  // wave 0..5 (SGPR)
    const int g = (w >= 3) ? 1 : 0;
    const int wg = w - g * 3;
    const int lane = tid & 63;
    const int ly = lane >> 4, lx = (lane & 15) + wg * 16;

    const int y0 = blockIdx.x * 4;
    const int ocb = blockIdx.y;
    const int b = blockIdx.z;
    const int y = y0 + ly, x = lx;
    const int oc0 = ocb * OCPB;

    const unsigned* wb = wt + (size_t)ocb * ICP * 9 * OCPB;

    const int obase = ((b * COUT + oc0) * 48 + y) * 48 + x;
    float rsv[OCPB];
#pragma unroll
    for (int o = 0; o < OCPB; ++o) rsv[o] = 0.f;
    if (MODE == M_ADD && tid < 192) {
#pragma unroll
        for (int o = 0; o < OCPB; ++o) rsv[o] = res[obase + o * 2304];
    }

    const int col = tid & 63, rg = tid >> 6;
    const unsigned* pbase = Pin + ((size_t)b * ICP * 50 + y0 + rg) * 64 + col;

    float acc[OCPB];
#pragma unroll
    for (int o = 0; o < OCPB; ++o) acc[o] = 0.f;

    for (int sc = 0; sc < NSC; ++sc) {
        const unsigned* p = pbase + (size_t)sc * (2 * SICP) * 3200;
        if (col < 50) {
#pragma unroll
            for (int j = 0; j < 2 * SICP; ++j) s_in[j][rg][col] = p[j * 3200];
        }
        __syncthreads();

#pragma unroll
        for (int jl = 0; jl < SICP; ++jl) {
            const int li = g * SICP + jl;
            unsigned f[3][3];
#pragma unroll
            for (int dy = 0; dy < 3; ++dy)
#pragma unroll
                for (int dx = 0; dx < 3; ++dx) f[dy][dx] = s_in[li][ly + dy][lx + dx];
            const uint4* wq =
                (const uint4*)(wb + (size_t)(sc * 2 * SICP + g * SICP + jl) * 9 * OCPB);
#pragma unroll
            for (int kk = 0; kk < 9; ++kk) {
                const h2 fv = __builtin_bit_cast(h2, f[kk / 3][kk % 3]);
                const unsigned AM = 0x7fff7fffu;
#pragma unroll
                for (int q = 0; q < NQ; ++q) {
                    const uint4 w4 = wq[kk * NQ + q];  // uniform addr -> s_load
                    {
                        h2 d = fv - __builtin_bit_cast(h2, w4.x);
                        acc[q * 4 + 0] =
                            fdot2_acc(__builtin_bit_cast(unsigned, d) & AM, acc[q * 4 + 0]);
                    }
                    {
                        h2 d = fv - __builtin_bit_cast(h2, w4.y);
                        acc[q * 4 + 1] =
                            fdot2_acc(__builtin_bit_cast(unsigned, d) & AM, acc[q * 4 + 1]);
                    }
                    {
                        h2 d = fv - __builtin_bit_cast(h2, w4.z);
                        acc[q * 4 + 2] =
                            fdot2_acc(__builtin_bit_cast(unsigned, d) & AM, acc[q * 4 + 2]);
                    }
                    {
                        h2 d = fv - __builtin_bit_cast(h2, w4.w);
                        acc[q * 4 + 3] =
                            fdot2_acc(__builtin_bit_cast(unsigned, d) & AM, acc[q * 4 + 3]);
                    }
                }
            }
        }
        __syncthreads();
    }

    // ---- cross-group reduce (reuse s_in as scratch) ----
    float* s_red = (float*)&s_in[0][0][0];
    if (tid >= 192) {
#pragma unroll
        for (int q = 0; q < NQ; ++q) {
            float4 a4 = {acc[q * 4 + 0], acc[q * 4 + 1], acc[q * 4 + 2], acc[q * 4 + 3]};
            *(float4*)&s_red[(tid - 192) * OCPB + q * 4] = a4;
        }
    }
    __syncthreads();
    if (tid >= 192) return;
#pragma unroll
    for (int q = 0; q < NQ; ++q) {
        const float4 a4 = *(const float4*)&s_red[tid * OCPB + q * 4];
        acc[q * 4 + 0] += a4.x;
        acc[q * 4 + 1] += a4.y;
        acc[q * 4 + 2] += a4.z;
        acc[q * 4 + 3] += a4.w;
    }

    // ---- epilogue (192 threads) ----
    float v[OCPB];
#pragma unroll
    for (int o = 0; o < OCPB; ++o) {
        v[o] = acc[o];
        if (MODE == M_ADD) v[o] += rsv[o];
    }
    if (MODE == M_PS) {
#pragma unroll
        for (int o = 0; o < OCPB; ++o) {
            const int oc = oc0 + o;
            const int idx =
                ((b * 64 + (oc >> 2)) * 96 + 2 * y + ((oc >> 1) & 1)) * 96 + 2 * x + (oc & 1);
            outf[idx] = v[o];
        }
    } else {
        if (MODE == M_HEAD) {
#pragma unroll
            for (int o = 0; o < OCPB; ++o) outf[obase + o * 2304] = v[o];  // f32 h
        }
        float pv[OCPB];
#pragma unroll
        for (int o = 0; o < OCPB; ++o)
            pv[o] = (MODE == M_HEAD) ? v[o] + shp[oc0 + o] : v[o];
        const int pidx = ((b * (COUT / 2) + (oc0 >> 1)) * 50 + (y + 1)) * 64 + (x + 1);
#pragma unroll
        for (int j = 0; j < OCPB / 2; ++j) {
            h2 pk = __builtin_amdgcn_cvt_pkrtz(pv[2 * j], pv[2 * j + 1]);
            outp[pidx + j * 3200] = __builtin_bit_cast(unsigned, pk);
        }
    }
}

// ---- tail: conv 64->3 over ps[4][64][96][96], ic in 4 quarters ----
__global__ __launch_bounds__(256) void tail_kernel(const float* __restrict__ ps,
                                                   const float* __restrict__ tw,
                                                   const float* __restrict__ tb,
                                                   float* __restrict__ out) {
    __shared__ float s_w[432];
    const int tid = threadIdx.x;
    const int icq = blockIdx.y;
    for (int i = tid; i < 432; i += 256) {
        const int ic16 = i / 27, r = i % 27, kk = r / 3, oc = r % 3;
        s_w[(ic16 * 9 + kk) * 3 + oc] = tw[((oc * 64) + icq * 16 + ic16) * 9 + kk];
    }
    __syncthreads();

    const int gid = blockIdx.x * 256 + tid;
    const int b = gid / 9216;
    const int p = gid % 9216;
    const int Y = p / 96, X = p % 96;

    float a0 = 0.f, a1 = 0.f, a2 = 0.f;
    if (icq == 0) {
        a0 = tb[0] + mean_of(0);
        a1 = tb[1] + mean_of(1);
        a2 = tb[2] + mean_of(2);
    }
    const float* base = ps + ((size_t)b * 64 + icq * 16) * 9216;
    for (int ic = 0; ic < 16; ++ic) {
        const float* bp = base + ic * 9216;
#pragma unroll
        for (int kk = 0; kk < 9; ++kk) {
            const int yy = Y + kk / 3 - 1, xx = X + kk % 3 - 1;
            float fv = 0.f;
            if ((unsigned)yy < 96u && (unsigned)xx < 96u) fv = bp[yy * 96 + xx];
            const float* wr = &s_w[(ic * 9 + kk) * 3];
            a0 += fv * wr[0];
            a1 += fv * wr[1];
            a2 += fv * wr[2];
        }
    }
    atomicAdd(&out[((b * 3 + 0) * 96 + Y) * 96 + X], a0);
    atomicAdd(&out[((b * 3 + 1) * 96 + Y) * 96 + X], a1);
    atomicAdd(&out[((b * 3 + 2) * 96 + Y) * 96 + X], a2);
}

extern "C" void kernel_launch(void* const* d_in, const int* in_sizes, int n_in,
                              void* d_out, int out_size, void* d_ws, size_t ws_size,
                              hipStream_t stream) {
    const float* x      = (const float*)d_in[0];
    const float* head_w = (const float*)d_in[1];
    const float* rb_w2  = (const float*)d_in[3];
    const float* body_w = (const float*)d_in[4];
    const float* up_w   = (const float*)d_in[5];
    const float* tail_w = (const float*)d_in[6];
    const float* tail_b = (const float*)d_in[7];
    float* out = (float*)d_out;

    constexpr int S = 589824;   // 4*64*48*48
    constexpr int PK = 409600;  // 4*32*50*64 u32
    float* ws = (float*)d_ws;
    float* s0 = ws;          // f32 h
    float* ps = ws;          // 4S f32, overlays s0 (h dead at up-time)
    unsigned* pk_hs = (unsigned*)(ws + 4 * S);  // packed (h + shift)
    unsigned* pk_res = pk_hs + PK;              // packed res = h + body
    unsigned* px = pk_res + PK;                 // 25600
    unsigned* wtH = px + 25600;                 // 1152
    unsigned* wtB = wtH + 1152;                 // 18432
    unsigned* wtU = wtB + 18432;                // 73728
    float* shift = (float*)(wtU + 73728);       // 64

    // fused setup (weights, packx, shift, zero pk+out): one launch
    setup_kernel<<<dim3(893), dim3(256), 0, stream>>>(x, head_w, rb_w2, body_w, up_w,
                                                      px, wtH, wtB, wtU, shift, pk_hs,
                                                      out);

    const dim3 blk(384);
    // head: f32 h -> s0, packed(h+shift) -> pk_hs
    adder_kernel<2, 64, 4, M_HEAD><<<dim3(12, 16, 4), blk, 0, stream>>>(
        px, wtH, nullptr, shift, s0, pk_hs);
    // body: res = h + body(h+shift) -> packed pk_res
    adder_kernel<32, 64, 4, M_ADD><<<dim3(12, 16, 4), blk, 0, stream>>>(
        pk_hs, wtB, s0, nullptr, nullptr, pk_res);
    // up (COUT=256, 8 oc/thread) + fused pixel-shuffle -> f32 ps
    adder_kernel<32, 256, 8, M_PS><<<dim3(12, 32, 4), blk, 0, stream>>>(
        pk_res, wtU, nullptr, nullptr, ps, nullptr);
    // tail conv (4 ic-quarters, atomic)
    tail_kernel<<<dim3(144, 4), dim3(256), 0, stream>>>(ps, tail_w, tail_b, out);
}

// Round 10
// 126.591 us; speedup vs baseline: 149.4858x; 1.5574x over previous
//
#include <hip/hip_runtime.h>

// AdderNet-EDSR on MI355X. v10: FULL LINEAR COLLAPSE.
// (1) adder2d <= 0 always => relu(adder)==0 => residual chain = per-channel
//     constant shift[ic] = -0.1*Sum_k Sum|rb_w2| (~ -18).
// (2) body input bin = h+shift <= -17 < min weight => |bin-w| = w-bin EXACTLY
//     => body[oc] = BoxIn(T) - Cb_oc(border pattern), T = H + c0,
//        H = Sum_oc h[oc], c0 = Sum shift, BoxIn = 3x3 zero-pad box-sum.
// (3) res = h+body <= -4000 < min up weight => up[oc] = BoxIn(U) - Cu_oc(pat),
//     U = H + 64*BoxIn(T) - D(pat), D = Sum_oc Cb_oc.
// (4) pixel-shuffle+tail conv on up = 9-tap stencil on V = BoxIn(U):
//     out[c](Y,X) = Sum_{taps in-bounds} [A_c[kk]*V(yy,xx) - E_c[kk,pr,pat]]
//                   + tb_c + mean_c,  yy=(Y+dy)>>1, pr=parities, pat=border.
// Only the head (64 oc x 3 ic x 9 taps) remains a true adder layer. Everything
// f32 (absmax should drop to O(1)). 4 dispatches.

__device__ __forceinline__ float mean_of(int c) {
    return c == 0 ? 0.4488f : (c == 1 ? 0.4371f : 0.404f);
}

// ws float offsets
#define OFF_H 0        // 9216
#define OFF_V 9216     // 9216
#define OFF_SHIFT 18432  // 64
#define OFF_SSB 18496    // 9   Sum_{oc,ic} body_w per tap
#define OFF_AAB 18505    // 9   Sum_{oc,ic}|body_w| per tap
#define OFF_A 18514      // 27  A[kk*3+c] = Sum_ic tail_w
#define OFF_E 18541      // 972 E[kk*108 + pr*27 + pat*3 + c]

// ---- K1 setup: shift (64 blocks) | SSb/AAb (9 blocks) | tables (1 block) ----
__global__ __launch_bounds__(256) void setup_kernel(const float* __restrict__ rb_w2,
                                                    const float* __restrict__ body_w,
                                                    const float* __restrict__ up_w,
                                                    const float* __restrict__ tail_w,
                                                    float* __restrict__ ws) {
    __shared__ float s_a[256], s_b[256];
    const int bx = blockIdx.x, tid = threadIdx.x;

    if (bx < 64) {  // shift[oc] = -0.1 * Sum_k Sum_{ic,kk} |rb_w2[k][oc]|
        const int oc = bx;
        float s = 0.f;
        for (int e = tid; e < 4608; e += 256)
            s += fabsf(rb_w2[(e / 576) * 36864 + oc * 576 + (e % 576)]);
        s_a[tid] = s;
        __syncthreads();
        for (int st = 128; st > 0; st >>= 1) {
            if (tid < st) s_a[tid] += s_a[tid + st];
            __syncthreads();
        }
        if (tid == 0) ws[OFF_SHIFT + oc] = -0.1f * s_a[0];
    } else if (bx < 73) {  // SSb[kk], AAb[kk]: reduce over oc*64+ic = 0..4095
        const int kk = bx - 64;
        float ss = 0.f, aa = 0.f;
        for (int i = tid; i < 4096; i += 256) {
            const float v = body_w[i * 9 + kk];
            ss += v;
            aa += fabsf(v);
        }
        s_a[tid] = ss;
        s_b[tid] = aa;
        __syncthreads();
        for (int st = 128; st > 0; st >>= 1) {
            if (tid < st) {
                s_a[tid] += s_a[tid + st];
                s_b[tid] += s_b[tid + st];
            }
            __syncthreads();
        }
        if (tid == 0) {
            ws[OFF_SSB + kk] = s_a[0];
            ws[OFF_AAB + kk] = s_b[0];
        }
    } else {  // tables block: Cu (LDS), A, E
        __shared__ float s_cu[9 * 256];  // [pat][oc]
        // per-oc Su/Au over ic, then Cu for 9 patterns
        const int oc = tid;  // 0..255
        float Su[9], Au[9];
#pragma unroll
        for (int kk = 0; kk < 9; ++kk) {
            Su[kk] = 0.f;
            Au[kk] = 0.f;
        }
        for (int ic = 0; ic < 64; ++ic) {
#pragma unroll
            for (int kk = 0; kk < 9; ++kk) {
                const float v = up_w[oc * 576 + ic * 9 + kk];
                Su[kk] += v;
                Au[kk] += fabsf(v);
            }
        }
        for (int pat = 0; pat < 9; ++pat) {
            const int cy = pat / 3, cx = pat % 3;
            float cu = 0.f;
#pragma unroll
            for (int kk = 0; kk < 9; ++kk) {
                const int i = kk / 3, j = kk % 3;
                const bool iny = (i == 1) || (i == 0 && cy > 0) || (i == 2 && cy < 2);
                const bool inx = (j == 1) || (j == 0 && cx > 0) || (j == 2 && cx < 2);
                cu += (iny && inx) ? Su[kk] : Au[kk];
            }
            s_cu[pat * 256 + oc] = cu;
        }
        __syncthreads();
        // A[kk*3+c] = Sum_ic tail_w[c][ic][kk]
        if (tid < 27) {
            const int kk = tid / 3, c = tid % 3;
            float a = 0.f;
            for (int ic = 0; ic < 64; ++ic) a += tail_w[c * 576 + ic * 9 + kk];
            ws[OFF_A + kk * 3 + c] = a;
        }
        // E[kk*108 + pr*27 + pat*3 + c] = Sum_ic tail_w[c][ic][kk]*Cu[pat][4ic+pr]
        for (int e = tid; e < 972; e += 256) {
            const int kk = e / 108, r = e % 108;
            const int pr = r / 27, r2 = r % 27;
            const int pat = r2 / 3, c = r2 % 3;
            float acc = 0.f;
            for (int ic = 0; ic < 64; ++ic)
                acc += tail_w[c * 576 + ic * 9 + kk] * s_cu[pat * 256 + 4 * ic + pr];
            ws[OFF_E + e] = acc;
        }
    }
}

// ---- K2 head: H(px) = Sum_oc -Sum_{ic,kk}|win - hw| (win=0 for pad: |0-w|=|w|)
// block 256 = 64 px x 4 oc-quarters; grid 144 (9216 px). ----
__global__ __launch_bounds__(256) void headH_kernel(const float* __restrict__ x,
                                                    const float* __restrict__ head_w,
                                                    float* __restrict__ ws) {
    __shared__ float s_hw[1728];
    __shared__ float s_red[64][4];
    const int tid = threadIdx.x;
    for (int i = tid; i < 1728; i += 256) s_hw[i] = head_w[i];

    const int p = tid & 63, q = tid >> 6;
    const int px = blockIdx.x * 64 + p;
    const int b = px / 2304, rem = px % 2304;
    const int y = rem / 48, xx = rem % 48;

    float win[3][9];
#pragma unroll
    for (int ic = 0; ic < 3; ++ic)
#pragma unroll
        for (int kk = 0; kk < 9; ++kk) {
            const int gy = y + kk / 3 - 1, gx = xx + kk % 3 - 1;
            win[ic][kk] = ((unsigned)gy < 48u && (unsigned)gx < 48u)
                              ? x[((b * 3 + ic) * 48 + gy) * 48 + gx] - mean_of(ic)
                              : 0.f;
        }
    __syncthreads();

    float acc = 0.f;
    for (int o = 0; o < 16; ++o) {
        const int oc = q * 16 + o;
#pragma unroll
        for (int ic = 0; ic < 3; ++ic)
#pragma unroll
            for (int kk = 0; kk < 9; ++kk)
                acc -= fabsf(win[ic][kk] - s_hw[oc * 27 + ic * 9 + kk]);
    }
    s_red[p][q] = acc;
    __syncthreads();
    if (q == 0)
        ws[OFF_H + px] = s_red[p][0] + s_red[p][1] + s_red[p][2] + s_red[p][3];
}

// ---- K3 planes: T = H + c0; B = BoxIn(T); U = H + 64B - D(pat); V = BoxIn(U).
// One block per batch, 576 threads x 4 px. ----
__global__ __launch_bounds__(576) void planes_kernel(float* __restrict__ ws) {
    __shared__ float Tp[50][52];  // zero-padded T
    __shared__ float Up[50][52];  // zero-padded U
    __shared__ float s_sh[64], s_sb[9], s_ab[9];
    const int tid = threadIdx.x;
    const int b = blockIdx.x;

    if (tid < 64) s_sh[tid] = ws[OFF_SHIFT + tid];
    if (tid >= 64 && tid < 73) s_sb[tid - 64] = ws[OFF_SSB + tid - 64];
    if (tid >= 73 && tid < 82) s_ab[tid - 73] = ws[OFF_AAB + tid - 73];
    for (int i = tid; i < 2600; i += 576) {
        ((float*)Tp)[i] = 0.f;
        ((float*)Up)[i] = 0.f;
    }
    __syncthreads();

    float c0 = 0.f;
    for (int i = 0; i < 64; ++i) c0 += s_sh[i];

    float Hv[4];
#pragma unroll
    for (int j = 0; j < 4; ++j) {
        const int px = tid + j * 576;
        Hv[j] = ws[OFF_H + b * 2304 + px];
        Tp[1 + px / 48][1 + px % 48] = Hv[j] + c0;
    }
    __syncthreads();

#pragma unroll
    for (int j = 0; j < 4; ++j) {
        const int px = tid + j * 576;
        const int y = px / 48, xx = px % 48;
        float B = 0.f, D = 0.f;
#pragma unroll
        for (int kk = 0; kk < 9; ++kk) {
            const int i = kk / 3, jj = kk % 3;
            B += Tp[y + i][xx + jj];
            const bool iny = (i == 1) || (i == 0 && y > 0) || (i == 2 && y < 47);
            const bool inx = (jj == 1) || (jj == 0 && xx > 0) || (jj == 2 && xx < 47);
            D += (iny && inx) ? s_sb[kk] : s_ab[kk];
        }
        Up[1 + y][1 + xx] = Hv[j] + 64.f * B - D;
    }
    __syncthreads();

#pragma unroll
    for (int j = 0; j < 4; ++j) {
        const int px = tid + j * 576;
        const int y = px / 48, xx = px % 48;
        float V = 0.f;
#pragma unroll
        for (int kk = 0; kk < 9; ++kk) V += Up[y + kk / 3][xx + kk % 3];
        ws[OFF_V + b * 2304 + px] = V;
    }
}

// ---- K4 tail: out[c](Y,X) = Sum_{taps in} [A_c*V(yy,xx) - E_c(kk,pr,pat)]
// + tb_c + mean_c. block 256, grid 144 (36 blocks/batch). ----
__global__ __launch_bounds__(256) void tail_kernel(const float* __restrict__ ws,
                                                   const float* __restrict__ tb,
                                                   float* __restrict__ out) {
    __shared__ float sV[2304];
    __shared__ float sA[27], sE[972];
    const int tid = threadIdx.x;
    const int b = blockIdx.x / 36;
    const int pxb = (blockIdx.x % 36) * 256 + tid;

    for (int i = tid; i < 2304; i += 256) sV[i] = ws[OFF_V + b * 2304 + i];
    if (tid < 27) sA[tid] = ws[OFF_A + tid];
    for (int i = tid; i < 972; i += 256) sE[i] = ws[OFF_E + i];
    __syncthreads();

    const int Y = pxb / 96, X = pxb % 96;
    float acc0 = tb[0] + mean_of(0);
    float acc1 = tb[1] + mean_of(1);
    float acc2 = tb[2] + mean_of(2);

#pragma unroll
    for (int kk = 0; kk < 9; ++kk) {
        const int Yt = Y + kk / 3 - 1, Xt = X + kk % 3 - 1;
        if ((unsigned)Yt < 96u && (unsigned)Xt < 96u) {
            const int yy = Yt >> 1, xx = Xt >> 1;
            const float Vv = sV[yy * 48 + xx];
            const int cy = (yy == 0) ? 0 : ((yy == 47) ? 2 : 1);
            const int cx = (xx == 0) ? 0 : ((xx == 47) ? 2 : 1);
            const int pat = cy * 3 + cx;
            const int pr = ((Yt & 1) << 1) | (Xt & 1);
            const int eb = kk * 108 + pr * 27 + pat * 3;
            acc0 += sA[kk * 3 + 0] * Vv - sE[eb + 0];
            acc1 += sA[kk * 3 + 1] * Vv - sE[eb + 1];
            acc2 += sA[kk * 3 + 2] * Vv - sE[eb + 2];
        }
    }
    out[((b * 3 + 0) * 96 + Y) * 96 + X] = acc0;
    out[((b * 3 + 1) * 96 + Y) * 96 + X] = acc1;
    out[((b * 3 + 2) * 96 + Y) * 96 + X] = acc2;
}

extern "C" void kernel_launch(void* const* d_in, const int* in_sizes, int n_in,
                              void* d_out, int out_size, void* d_ws, size_t ws_size,
                              hipStream_t stream) {
    const float* x      = (const float*)d_in[0];
    const float* head_w = (const float*)d_in[1];
    const float* rb_w2  = (const float*)d_in[3];
    const float* body_w = (const float*)d_in[4];
    const float* up_w   = (const float*)d_in[5];
    const float* tail_w = (const float*)d_in[6];
    const float* tail_b = (const float*)d_in[7];
    float* out = (float*)d_out;
    float* ws = (float*)d_ws;

    setup_kernel<<<dim3(74), dim3(256), 0, stream>>>(rb_w2, body_w, up_w, tail_w, ws);
    headH_kernel<<<dim3(144), dim3(256), 0, stream>>>(x, head_w, ws);
    planes_kernel<<<dim3(4), dim3(576), 0, stream>>>(ws);
    tail_kernel<<<dim3(144), dim3(256), 0, stream>>>(ws, tail_b, out);
}

// Round 11
// 95.938 us; speedup vs baseline: 197.2469x; 1.3195x over previous
//
#include <hip/hip_runtime.h>

// AdderNet-EDSR on MI355X. v11 = v10's full linear collapse + parallelized
// setup (the 47us latency-bound tables/shift blocks were the top dispatch).
// Math (all proven exact in v8/v10, passed at absmax 32768 << 1.9e5):
//  (1) adder2d <= 0 => relu==0 => residual chain = const shift; only c0 =
//      Sum_oc shift = -0.1*Sum|rb_w2| is ever consumed.
//  (2) body input <= -17 < w => |in-w| = w-in exactly => body linear:
//      body = BoxIn(T) - Cb(pat), T = H + c0, H = channel-sum of head.
//  (3) up likewise: up[oc] = BoxIn(U) - Cu_oc(pat), U = H + 64*BoxIn(T) - D(pat).
//  (4) PS + tail conv = 9-tap stencil on V = BoxIn(U) with per-(c,tap,parity,
//      border-pattern) constants A/E.
// v11 layout: K1 (296 blk: c0-partials | body-partials | up Su/Au | headH),
// K2 (4 planes blk + 1 tables blk), K3 tail. 3 dispatches, all reductions
// coalesced + LDS-tree.

__device__ __forceinline__ float mean_of(int c) {
    return c == 0 ? 0.4488f : (c == 1 ? 0.4371f : 0.404f);
}

// ws float offsets
#define OFF_H 0          // 9216
#define OFF_V 9216       // 9216
#define OFF_C0P 18432    // 72   partials of Sum|rb_w2|
#define OFF_SBP 18504    // 144  body Sum(w) partials [16 blk][9 tap]
#define OFF_ABP 18648    // 144  body Sum|w| partials (contiguous after SBP)
#define OFF_SU 18792     // 2304 up Sum_ic(w) [oc][tap]
#define OFF_AU 21096     // 2304 up Sum_ic|w| [oc][tap]
#define OFF_A 23400      // 27   A[kk*3+c] = Sum_ic tail_w
#define OFF_E 23427      // 972  E[kk*108 + pr*27 + pat*3 + c]

// ---- K1: c0 partials (72) | body partials (16) | up Su/Au (64) | headH (144) ----
__global__ __launch_bounds__(256) void setup1_kernel(const float* __restrict__ x,
                                                     const float* __restrict__ head_w,
                                                     const float* __restrict__ rb_w2,
                                                     const float* __restrict__ body_w,
                                                     const float* __restrict__ up_w,
                                                     float* __restrict__ ws) {
    const int bx = blockIdx.x, tid = threadIdx.x;

    if (bx < 72) {  // c0 partial: |rb_w2| over 4096 contiguous floats
        __shared__ float s_a[256];
        float s = 0.f;
        const float* p = rb_w2 + bx * 4096;
#pragma unroll
        for (int i = 0; i < 16; ++i) s += fabsf(p[tid + i * 256]);
        s_a[tid] = s;
        __syncthreads();
        for (int st = 128; st > 0; st >>= 1) {
            if (tid < st) s_a[tid] += s_a[tid + st];
            __syncthreads();
        }
        if (tid == 0) ws[OFF_C0P + bx] = s_a[0];
    } else if (bx < 88) {  // body partials: pair p reads 9 contiguous floats
        __shared__ float s_m[256][18];
        const int pr = (bx - 72) * 256 + tid;  // (oc,ic) pair 0..4095
        const float* p = body_w + pr * 9;
#pragma unroll
        for (int k = 0; k < 9; ++k) {
            const float v = p[k];
            s_m[tid][k] = v;
            s_m[tid][9 + k] = fabsf(v);
        }
        __syncthreads();
        for (int st = 128; st > 0; st >>= 1) {
            if (tid < st)
#pragma unroll
                for (int k = 0; k < 18; ++k) s_m[tid][k] += s_m[tid + st][k];
            __syncthreads();
        }
        if (tid < 18) {
            const int blk = bx - 72;
            if (tid < 9)
                ws[OFF_SBP + blk * 9 + tid] = s_m[0][tid];
            else
                ws[OFF_ABP + blk * 9 + (tid - 9)] = s_m[0][tid];
        }
    } else if (bx < 152) {  // up Su/Au: 4 oc per block, reduce over 64 ic
        __shared__ float s_m[256][18];
        const int g = tid >> 6, ic = tid & 63;
        const int oc = (bx - 88) * 4 + g;
        const float* p = up_w + oc * 576 + ic * 9;
#pragma unroll
        for (int k = 0; k < 9; ++k) {
            const float v = p[k];
            s_m[tid][k] = v;
            s_m[tid][9 + k] = fabsf(v);
        }
        __syncthreads();
        for (int st = 32; st > 0; st >>= 1) {
            if (ic < st)
#pragma unroll
                for (int k = 0; k < 18; ++k) s_m[tid][k] += s_m[tid + st][k];
            __syncthreads();
        }
        if (ic < 18) {
            if (ic < 9)
                ws[OFF_SU + oc * 9 + ic] = s_m[g * 64][ic];
            else
                ws[OFF_AU + oc * 9 + (ic - 9)] = s_m[g * 64][ic];
        }
    } else {  // headH: H(px) = -Sum_oc Sum_{ic,kk} |win - hw|
        __shared__ float s_hw[1728];
        __shared__ float s_red[64][4];
        for (int i = tid; i < 1728; i += 256) s_hw[i] = head_w[i];

        const int p = tid & 63, q = tid >> 6;
        const int px = (bx - 152) * 64 + p;
        const int b = px / 2304, rem = px % 2304;
        const int y = rem / 48, xx = rem % 48;

        float win[3][9];
#pragma unroll
        for (int ic = 0; ic < 3; ++ic)
#pragma unroll
            for (int kk = 0; kk < 9; ++kk) {
                const int gy = y + kk / 3 - 1, gx = xx + kk % 3 - 1;
                win[ic][kk] = ((unsigned)gy < 48u && (unsigned)gx < 48u)
                                  ? x[((b * 3 + ic) * 48 + gy) * 48 + gx] - mean_of(ic)
                                  : 0.f;
            }
        __syncthreads();

        float acc = 0.f;
        for (int o = 0; o < 16; ++o) {
            const int oc = q * 16 + o;
#pragma unroll
            for (int ic = 0; ic < 3; ++ic)
#pragma unroll
                for (int kk = 0; kk < 9; ++kk)
                    acc -= fabsf(win[ic][kk] - s_hw[oc * 27 + ic * 9 + kk]);
        }
        s_red[p][q] = acc;
        __syncthreads();
        if (q == 0)
            ws[OFF_H + px] = s_red[p][0] + s_red[p][1] + s_red[p][2] + s_red[p][3];
    }
}

// ---- K2: planes (bx<4) + tables (bx==4), 576 threads ----
__global__ __launch_bounds__(576) void setup2_kernel(const float* __restrict__ tail_w,
                                                     float* __restrict__ ws) {
    const int tid = threadIdx.x;
    const int bx = blockIdx.x;

    if (bx < 4) {  // planes: T = H + c0; B = BoxIn(T); U = H + 64B - D; V = BoxIn(U)
        __shared__ float Tp[50][52];
        __shared__ float Up[50][52];
        __shared__ float s_p[288];   // body partials staged
        __shared__ float s_r[128];   // c0 reduce
        __shared__ float s_c0;
        __shared__ float s_sb[9], s_ab[9];
        const int b = bx;

        if (tid < 128) s_r[tid] = 0.f;
        if (tid < 288) s_p[tid] = ws[OFF_SBP + tid];  // SBP(144) + ABP(144) contiguous
        for (int i = tid; i < 2600; i += 576) {
            ((float*)Tp)[i] = 0.f;
            ((float*)Up)[i] = 0.f;
        }
        __syncthreads();
        if (tid < 72) s_r[tid] = ws[OFF_C0P + tid];
        __syncthreads();
        for (int st = 64; st > 0; st >>= 1) {
            if (tid < st) s_r[tid] += s_r[tid + st];
            __syncthreads();
        }
        if (tid == 0) s_c0 = -0.1f * s_r[0];
        if (tid < 9) {
            float ss = 0.f, aa = 0.f;
#pragma unroll
            for (int r = 0; r < 16; ++r) {
                ss += s_p[r * 9 + tid];
                aa += s_p[144 + r * 9 + tid];
            }
            s_sb[tid] = ss;
            s_ab[tid] = aa;
        }
        __syncthreads();

        const float c0 = s_c0;
        float Hv[4];
#pragma unroll
        for (int j = 0; j < 4; ++j) {
            const int px = tid + j * 576;
            Hv[j] = ws[OFF_H + b * 2304 + px];
            Tp[1 + px / 48][1 + px % 48] = Hv[j] + c0;
        }
        __syncthreads();

#pragma unroll
        for (int j = 0; j < 4; ++j) {
            const int px = tid + j * 576;
            const int y = px / 48, xx = px % 48;
            float B = 0.f, D = 0.f;
#pragma unroll
            for (int kk = 0; kk < 9; ++kk) {
                const int i = kk / 3, jj = kk % 3;
                B += Tp[y + i][xx + jj];
                const bool iny = (i == 1) || (i == 0 && y > 0) || (i == 2 && y < 47);
                const bool inx = (jj == 1) || (jj == 0 && xx > 0) || (jj == 2 && xx < 47);
                D += (iny && inx) ? s_sb[kk] : s_ab[kk];
            }
            Up[1 + y][1 + xx] = Hv[j] + 64.f * B - D;
        }
        __syncthreads();

#pragma unroll
        for (int j = 0; j < 4; ++j) {
            const int px = tid + j * 576;
            const int y = px / 48, xx = px % 48;
            float V = 0.f;
#pragma unroll
            for (int kk = 0; kk < 9; ++kk) V += Up[y + kk / 3][xx + kk % 3];
            ws[OFF_V + b * 2304 + px] = V;
        }
    } else {  // tables: Cu (LDS), A, E — all inputs small and LDS-staged
        __shared__ float s_tw[1728];
        __shared__ float s_su[2304], s_au[2304];
        __shared__ float s_cu[2304];  // [pat][oc]
        for (int i = tid; i < 1728; i += 576) s_tw[i] = tail_w[i];
        for (int i = tid; i < 2304; i += 576) {
            s_su[i] = ws[OFF_SU + i];
            s_au[i] = ws[OFF_AU + i];
        }
        __syncthreads();
        for (int e = tid; e < 2304; e += 576) {  // Cu[pat*256+oc]
            const int pat = e >> 8, oc = e & 255;
            const int cy = pat / 3, cx = pat % 3;
            float cu = 0.f;
#pragma unroll
            for (int kk = 0; kk < 9; ++kk) {
                const int i = kk / 3, j = kk % 3;
                const bool iny = (i == 1) || (i == 0 && cy > 0) || (i == 2 && cy < 2);
                const bool inx = (j == 1) || (j == 0 && cx > 0) || (j == 2 && cx < 2);
                cu += (iny && inx) ? s_su[oc * 9 + kk] : s_au[oc * 9 + kk];
            }
            s_cu[e] = cu;
        }
        __syncthreads();
        if (tid < 27) {  // A[kk*3+c]
            const int kk = tid / 3, c = tid % 3;
            float a = 0.f;
            for (int ic = 0; ic < 64; ++ic) a += s_tw[c * 576 + ic * 9 + kk];
            ws[OFF_A + tid] = a;
        }
        for (int e = tid; e < 972; e += 576) {  // E[kk*108 + pr*27 + pat*3 + c]
            const int kk = e / 108, r = e % 108;
            const int pr = r / 27, r2 = r % 27;
            const int pat = r2 / 3, c = r2 % 3;
            float acc = 0.f;
            for (int ic = 0; ic < 64; ++ic)
                acc += s_tw[c * 576 + ic * 9 + kk] * s_cu[pat * 256 + 4 * ic + pr];
            ws[OFF_E + e] = acc;
        }
    }
}

// ---- K3 tail: out[c](Y,X) = Sum_{taps in} [A_c*V - E_c(kk,pr,pat)] + tb + mean ----
__global__ __launch_bounds__(256) void tail_kernel(const float* __restrict__ ws,
                                                   const float* __restrict__ tb,
                                                   float* __restrict__ out) {
    __shared__ float sV[2304];
    __shared__ float sA[27], sE[972];
    const int tid = threadIdx.x;
    const int b = blockIdx.x / 36;
    const int pxb = (blockIdx.x % 36) * 256 + tid;

    for (int i = tid; i < 2304; i += 256) sV[i] = ws[OFF_V + b * 2304 + i];
    if (tid < 27) sA[tid] = ws[OFF_A + tid];
    for (int i = tid; i < 972; i += 256) sE[i] = ws[OFF_E + i];
    __syncthreads();

    const int Y = pxb / 96, X = pxb % 96;
    float acc0 = tb[0] + mean_of(0);
    float acc1 = tb[1] + mean_of(1);
    float acc2 = tb[2] + mean_of(2);

#pragma unroll
    for (int kk = 0; kk < 9; ++kk) {
        const int Yt = Y + kk / 3 - 1, Xt = X + kk % 3 - 1;
        if ((unsigned)Yt < 96u && (unsigned)Xt < 96u) {
            const int yy = Yt >> 1, xx = Xt >> 1;
            const float Vv = sV[yy * 48 + xx];
            const int cy = (yy == 0) ? 0 : ((yy == 47) ? 2 : 1);
            const int cx = (xx == 0) ? 0 : ((xx == 47) ? 2 : 1);
            const int pat = cy * 3 + cx;
            const int pr = ((Yt & 1) << 1) | (Xt & 1);
            const int eb = kk * 108 + pr * 27 + pat * 3;
            acc0 += sA[kk * 3 + 0] * Vv - sE[eb + 0];
            acc1 += sA[kk * 3 + 1] * Vv - sE[eb + 1];
            acc2 += sA[kk * 3 + 2] * Vv - sE[eb + 2];
        }
    }
    out[((b * 3 + 0) * 96 + Y) * 96 + X] = acc0;
    out[((b * 3 + 1) * 96 + Y) * 96 + X] = acc1;
    out[((b * 3 + 2) * 96 + Y) * 96 + X] = acc2;
}

extern "C" void kernel_launch(void* const* d_in, const int* in_sizes, int n_in,
                              void* d_out, int out_size, void* d_ws, size_t ws_size,
                              hipStream_t stream) {
    const float* x      = (const float*)d_in[0];
    const float* head_w = (const float*)d_in[1];
    const float* rb_w2  = (const float*)d_in[3];
    const float* body_w = (const float*)d_in[4];
    const float* up_w   = (const float*)d_in[5];
    const float* tail_w = (const float*)d_in[6];
    const float* tail_b = (const float*)d_in[7];
    float* out = (float*)d_out;
    float* ws = (float*)d_ws;

    setup1_kernel<<<dim3(296), dim3(256), 0, stream>>>(x, head_w, rb_w2, body_w, up_w,
                                                       ws);
    setup2_kernel<<<dim3(5), dim3(576), 0, stream>>>(tail_w, ws);
    tail_kernel<<<dim3(144), dim3(256), 0, stream>>>(ws, tail_b, out);
}